// Round 10
// baseline (420.181 us; speedup 1.0000x reference)
//
#include <hip/hip_runtime.h>
#include <cmath>

// Decoder_spirals R9: LDS-free spiral convs.
// conv_nolds / out_nolds load MFMA fragments DIRECTLY from global (gather rows are
// 16B-aligned contiguous per-lane slices; weights L1/L2-resident) -- no LDS, no
// barriers, no staging round-trip. Upsamples keep R8's 3-buffer counted-vmcnt gload
// pipeline (at m97-structure ceiling ~710TF for U0).

#define NB 16

typedef __attribute__((ext_vector_type(8))) short bf16x8;
typedef __attribute__((ext_vector_type(4))) float f32x4;

__device__ __forceinline__ unsigned short f2bf(float x) {
    union { float f; unsigned u; } v; v.f = x;
    unsigned r = v.u + 0x7FFFu + ((v.u >> 16) & 1u);
    return (unsigned short)(r >> 16);
}
__device__ __forceinline__ void gload16(const void* src, void* dst) {
    __builtin_amdgcn_global_load_lds(
        (const __attribute__((address_space(1))) unsigned int*)src,
        (__attribute__((address_space(3))) unsigned int*)dst, 16, 0, 0);
}

// ---------------- converters ----------------
__global__ __launch_bounds__(256) void cvt_ub(const float* __restrict__ src,
                                              unsigned short* __restrict__ dst,
                                              int V, int W, int Wp) {
    int k = blockIdx.x * 256 + threadIdx.x;
    int row = blockIdx.y;
    if (k >= Wp) return;
    float v = (row < V && k < W) ? src[(size_t)row * W + k] : 0.f;
    dst[(size_t)row * Wp + k] = f2bf(v);
}
__global__ __launch_bounds__(256) void cvt_wT(const float* __restrict__ w,
                                              unsigned short* __restrict__ wT,
                                              int K, int N, int total) {
    int id = blockIdx.x * 256 + threadIdx.x;
    if (id >= total) return;
    int n = id / K, k = id - n * K;
    wT[id] = f2bf(w[(size_t)k * N + n]);
}
__global__ __launch_bounds__(256) void cvt_w2(const float* __restrict__ w,
                                              unsigned short* __restrict__ wt) {
    int id = blockIdx.x * 256 + threadIdx.x;
    if (id >= 16 * 1288) return;
    int n = id / 1288, k = id - n * 1288;
    float v = (n < 3 && k < 1280) ? w[(size_t)k * 3 + n] : 0.f;
    wt[id] = f2bf(v);
}
__global__ __launch_bounds__(256) void cvt_sT(const int* __restrict__ S,
                                              int* __restrict__ ST,
                                              int V, int K, int total) {
    int id = blockIdx.x * 256 + threadIdx.x;
    if (id >= total) return;
    int k = id / V, v = id - k * V;
    ST[id] = S[(size_t)v * K + k];
}
__global__ __launch_bounds__(256) void zero16(int4* __restrict__ p, int n16) {
    int id = blockIdx.x * 256 + threadIdx.x;
    if (id < n16) p[id] = make_int4(0, 0, 0, 0);
}

// ---------------- FC: z(16,128)@Wfc(128,23680)+bfc -> x3T[b*128+f][192] bf16 ----------------
__global__ __launch_bounds__(256) void fc_kernel(const float* __restrict__ z,
                                                 const float* __restrict__ Wfc,
                                                 const float* __restrict__ bfc,
                                                 unsigned short* __restrict__ x3T) {
    const int N = 185 * 128;
    __shared__ float zs[NB * 128];
    int t = threadIdx.x;
    for (int i = t; i < NB * 128; i += 256) zs[i] = z[i];
    __syncthreads();
    int n = blockIdx.x * 256 + t;
    if (n >= N) return;
    float acc[NB];
#pragma unroll
    for (int b = 0; b < NB; ++b) acc[b] = 0.f;
    for (int k = 0; k < 128; ++k) {
        float w = Wfc[k * N + n];
#pragma unroll
        for (int b = 0; b < NB; ++b) acc[b] = fmaf(zs[b * 128 + k], w, acc[b]);
    }
    float bv = bfc[n];
    int f = n & 127, v = n >> 7;
#pragma unroll
    for (int b = 0; b < NB; ++b)
        x3T[(size_t)(b * 128 + f) * 192 + v] = f2bf(acc[b] + bv);
}

// ------------- Upsample: out[b,v,f] = sum_w U[v,w]*x[b,w,f] -------------
// 3-buffer, 2-deep prefetch, counted vmcnt(4), unrolled x3 (static buf indices).
template<int FSH, int VP>
__global__ __launch_bounds__(256) void ups_mfma(
    const unsigned short* __restrict__ Ub, const unsigned short* __restrict__ xT,
    unsigned short* __restrict__ out,
    int WpA, int WpB, int nsteps, int gxsh, int q) {
    const int F = 1 << FSH;
    __shared__ __align__(16) unsigned short As[3][128 * 32];
    __shared__ __align__(16) unsigned short Bs[3][128 * 32];
    const int t = threadIdx.x;
    const int wv = t >> 6, lane = t & 63;
    const int lr = lane & 15;

    const int flat = blockIdx.x;
    const int wg = (flat & 7) * q + (flat >> 3);
    const int m0 = (wg >> gxsh) * 128;
    const int n0 = (wg & ((1 << gxsh) - 1)) * 128;

    const int srow = lane >> 2;
    const int schunk = (((lane & 3) - ((lane >> 3) & 3)) & 3) * 8;
    const int ii0 = wv * 2, ii1 = wv * 2 + 1;
    const unsigned short* asrc0 = Ub + (size_t)(m0 + ii0 * 16 + srow) * WpA + schunk;
    const unsigned short* asrc1 = Ub + (size_t)(m0 + ii1 * 16 + srow) * WpA + schunk;
    const unsigned short* bsrc0 = xT + (size_t)(n0 + ii0 * 16 + srow) * WpB + schunk;
    const unsigned short* bsrc1 = xT + (size_t)(n0 + ii1 * 16 + srow) * WpB + schunk;

    const int fslot = (((lane >> 4) + (lr >> 1)) & 3) * 8;
    const int wrow = (wv >> 1) * 64;
    const int wcol = (wv & 1) * 64;
    const int u0 = wv * 1024;

    f32x4 acc[4][4];
#pragma unroll
    for (int i = 0; i < 4; ++i)
#pragma unroll
        for (int j = 0; j < 4; ++j) acc[i][j] = {0.f, 0.f, 0.f, 0.f};

#define UPS_STAGE(off_, B_)                                             \
    {                                                                   \
        gload16(asrc0 + (off_), &As[B_][u0]);                           \
        gload16(bsrc0 + (off_), &Bs[B_][u0]);                           \
        gload16(asrc1 + (off_), &As[B_][u0 + 512]);                     \
        gload16(bsrc1 + (off_), &Bs[B_][u0 + 512]);                     \
    }
#define UPS_COMPUTE(B_)                                                 \
    {                                                                   \
        bf16x8 af[4], bg[4];                                            \
        _Pragma("unroll")                                               \
        for (int mt = 0; mt < 4; ++mt)                                  \
            af[mt] = *(const bf16x8*)&As[B_][(wrow + mt * 16 + lr) * 32 + fslot]; \
        _Pragma("unroll")                                               \
        for (int nt = 0; nt < 4; ++nt)                                  \
            bg[nt] = *(const bf16x8*)&Bs[B_][(wcol + nt * 16 + lr) * 32 + fslot]; \
        _Pragma("unroll")                                               \
        for (int mt = 0; mt < 4; ++mt)                                  \
            _Pragma("unroll")                                           \
            for (int nt = 0; nt < 4; ++nt)                              \
                acc[mt][nt] = __builtin_amdgcn_mfma_f32_16x16x32_bf16(  \
                    af[mt], bg[nt], acc[mt][nt], 0, 0, 0);              \
    }
#define UPS_WAIT4 asm volatile("s_waitcnt vmcnt(4)" ::: "memory"); __builtin_amdgcn_s_barrier();
#define UPS_WAIT0 asm volatile("s_waitcnt vmcnt(0)" ::: "memory"); __builtin_amdgcn_s_barrier();

    // prologue: stage steps 0,1
    UPS_STAGE(0, 0);
    UPS_STAGE(32, 1);
    UPS_WAIT4;

    const int m = nsteps / 3;  // nsteps divisible by 3, m >= 2
    for (int it = 0; it < m - 1; ++it) {
        UPS_STAGE(64, 2);  UPS_COMPUTE(0); UPS_WAIT4;
        UPS_STAGE(96, 0);  UPS_COMPUTE(1); UPS_WAIT4;
        UPS_STAGE(128, 1); UPS_COMPUTE(2); UPS_WAIT4;
        asrc0 += 96; asrc1 += 96; bsrc0 += 96; bsrc1 += 96;
    }
    UPS_STAGE(64, 2);
    UPS_COMPUTE(0); UPS_WAIT4;
    UPS_COMPUTE(1); UPS_WAIT0;
    UPS_COMPUTE(2);
#undef UPS_STAGE
#undef UPS_COMPUTE
#undef UPS_WAIT4
#undef UPS_WAIT0

    // epilogue: C row=(lane>>4)*4+j (m), col=lane&15 (n); write bf16 [b][VP][F]
#pragma unroll
    for (int mt = 0; mt < 4; ++mt) {
        const int vb = m0 + wrow + mt * 16 + (lane >> 4) * 4;
#pragma unroll
        for (int nt = 0; nt < 4; ++nt) {
            const int col = n0 + wcol + nt * 16 + lr;
            const int b = col >> FSH, f = col & (F - 1);
            unsigned short* op = out + (size_t)b * VP * F + f;
#pragma unroll
            for (int j = 0; j < 4; ++j)
                op[(size_t)(vb + j) * F] = f2bf(acc[mt][nt][j]);
        }
    }
}

// ------- SpiralConv LDS-free: wave = 32x64, frags loaded directly from global -------
// Fin=128 fixed. A[row lr / 16+lr][k-chunk (lane>>4)*8] = contiguous 16B of gathered row.
// B rows from WT[n][Kdim]. No LDS, no barriers. bias+ELU+zero-dummy, transposed out.
__global__ __launch_bounds__(256) void conv_nolds(
    const unsigned short* __restrict__ xu, const int* __restrict__ ST,
    const unsigned short* __restrict__ WT, const float* __restrict__ bias,
    unsigned short* __restrict__ outT,
    int VT, int VP, int Ksp, int Kdim, int Fout) {
    const int t = threadIdx.x, wv = t >> 6, lane = t & 63;
    const int lr = lane & 15, lko = (lane >> 4) * 8;
    const int m0 = blockIdx.x * 128 + wv * 32;
    const int n0 = blockIdx.y * 64;
    const int b = m0 / VP;
    const int v0 = m0 - b * VP;
    const unsigned short* xb = xu + ((size_t)b * VP << 7);
    const int r0 = v0 + lr, r1 = v0 + 16 + lr;
    const int vg0 = r0 < VT ? r0 : VT - 1;
    const int vg1 = r1 < VT ? r1 : VT - 1;
    const unsigned short* wb0 = WT + (size_t)(n0 + lr) * Kdim + lko;
    const unsigned short* wb1 = wb0 + (size_t)16 * Kdim;
    const unsigned short* wb2 = wb0 + (size_t)32 * Kdim;
    const unsigned short* wb3 = wb0 + (size_t)48 * Kdim;

    f32x4 acc[2][4];
#pragma unroll
    for (int i = 0; i < 2; ++i)
#pragma unroll
        for (int j = 0; j < 4; ++j) acc[i][j] = {0.f, 0.f, 0.f, 0.f};

    int idx0 = ST[vg0];
    int idx1 = ST[vg1];
    for (int ks = 0; ks < Ksp; ++ks) {
        int ni0 = idx0, ni1 = idx1;
        if (ks + 1 < Ksp) {
            ni0 = ST[(size_t)(ks + 1) * VT + vg0];
            ni1 = ST[(size_t)(ks + 1) * VT + vg1];
        }
        const unsigned short* pa0 = xb + ((size_t)idx0 << 7) + lko;
        const unsigned short* pa1 = xb + ((size_t)idx1 << 7) + lko;
        const int kb = ks << 7;
#pragma unroll
        for (int sub = 0; sub < 4; ++sub) {
            bf16x8 a0 = *(const bf16x8*)(pa0 + sub * 32);
            bf16x8 a1 = *(const bf16x8*)(pa1 + sub * 32);
            bf16x8 g0 = *(const bf16x8*)(wb0 + kb + sub * 32);
            bf16x8 g1 = *(const bf16x8*)(wb1 + kb + sub * 32);
            bf16x8 g2 = *(const bf16x8*)(wb2 + kb + sub * 32);
            bf16x8 g3 = *(const bf16x8*)(wb3 + kb + sub * 32);
            acc[0][0] = __builtin_amdgcn_mfma_f32_16x16x32_bf16(a0, g0, acc[0][0], 0, 0, 0);
            acc[1][0] = __builtin_amdgcn_mfma_f32_16x16x32_bf16(a1, g0, acc[1][0], 0, 0, 0);
            acc[0][1] = __builtin_amdgcn_mfma_f32_16x16x32_bf16(a0, g1, acc[0][1], 0, 0, 0);
            acc[1][1] = __builtin_amdgcn_mfma_f32_16x16x32_bf16(a1, g1, acc[1][1], 0, 0, 0);
            acc[0][2] = __builtin_amdgcn_mfma_f32_16x16x32_bf16(a0, g2, acc[0][2], 0, 0, 0);
            acc[1][2] = __builtin_amdgcn_mfma_f32_16x16x32_bf16(a1, g2, acc[1][2], 0, 0, 0);
            acc[0][3] = __builtin_amdgcn_mfma_f32_16x16x32_bf16(a0, g3, acc[0][3], 0, 0, 0);
            acc[1][3] = __builtin_amdgcn_mfma_f32_16x16x32_bf16(a1, g3, acc[1][3], 0, 0, 0);
        }
        idx0 = ni0; idx1 = ni1;
    }

#pragma unroll
    for (int nt = 0; nt < 4; ++nt) {
        const int n = n0 + nt * 16 + lr;
        const float bv = bias[n];
        unsigned short* op = outT + (size_t)(b * Fout + n) * VP;
#pragma unroll
        for (int mt = 0; mt < 2; ++mt) {
            const int v = v0 + mt * 16 + (lane >> 4) * 4;
            ushort4 stv;
#pragma unroll
            for (int j = 0; j < 4; ++j) {
                float val = acc[mt][nt][j] + bv;
                val = val > 0.f ? val : expm1f(val);
                if (v + j == VT - 1) val = 0.f;
                ((unsigned short*)&stv)[j] = f2bf(val);
            }
            *(ushort4*)(op + v) = stv;
        }
    }
}

// ------- Final conv LDS-free: wave = 64x16 (3 cols used), K=1280, Fin=64 -------
__global__ __launch_bounds__(256) void out_nolds(
    const unsigned short* __restrict__ xu, const int* __restrict__ ST,
    const unsigned short* __restrict__ W2T, const float* __restrict__ b2,
    float* __restrict__ out) {
    const int VT = 11794, VP = 11904;
    const int t = threadIdx.x, wv = t >> 6, lane = t & 63;
    const int lr = lane & 15, lko = (lane >> 4) * 8;
    const int m0 = blockIdx.x * 256 + wv * 64;
    const int b = m0 / VP;
    const int v0 = m0 - b * VP;
    const unsigned short* xb = xu + ((size_t)b * VP << 6);
    int vg[4];
#pragma unroll
    for (int mt = 0; mt < 4; ++mt) {
        int r = v0 + mt * 16 + lr;
        vg[mt] = r < VT ? r : VT - 1;
    }
    const unsigned short* wrow = W2T + (size_t)lr * 1288 + lko;

    f32x4 acc[4];
#pragma unroll
    for (int i = 0; i < 4; ++i) acc[i] = {0.f, 0.f, 0.f, 0.f};

    int i0 = ST[vg[0]], i1 = ST[vg[1]], i2 = ST[vg[2]], i3 = ST[vg[3]];
    for (int ks = 0; ks < 20; ++ks) {
        int n0i = i0, n1i = i1, n2i = i2, n3i = i3;
        if (ks + 1 < 20) {
            const int* srow = ST + (size_t)(ks + 1) * VT;
            n0i = srow[vg[0]]; n1i = srow[vg[1]];
            n2i = srow[vg[2]]; n3i = srow[vg[3]];
        }
        const int kb = ks << 6;
#pragma unroll
        for (int sub = 0; sub < 2; ++sub) {
            bf16x8 bgv = *(const bf16x8*)(wrow + kb + sub * 32);
            bf16x8 a0 = *(const bf16x8*)(xb + ((size_t)i0 << 6) + sub * 32 + lko);
            bf16x8 a1 = *(const bf16x8*)(xb + ((size_t)i1 << 6) + sub * 32 + lko);
            bf16x8 a2 = *(const bf16x8*)(xb + ((size_t)i2 << 6) + sub * 32 + lko);
            bf16x8 a3 = *(const bf16x8*)(xb + ((size_t)i3 << 6) + sub * 32 + lko);
            acc[0] = __builtin_amdgcn_mfma_f32_16x16x32_bf16(a0, bgv, acc[0], 0, 0, 0);
            acc[1] = __builtin_amdgcn_mfma_f32_16x16x32_bf16(a1, bgv, acc[1], 0, 0, 0);
            acc[2] = __builtin_amdgcn_mfma_f32_16x16x32_bf16(a2, bgv, acc[2], 0, 0, 0);
            acc[3] = __builtin_amdgcn_mfma_f32_16x16x32_bf16(a3, bgv, acc[3], 0, 0, 0);
        }
        i0 = n0i; i1 = n1i; i2 = n2i; i3 = n3i;
    }

    if (lr < 3) {
        const float bv = b2[lr];
#pragma unroll
        for (int mt = 0; mt < 4; ++mt) {
#pragma unroll
            for (int j = 0; j < 4; ++j) {
                const int vv = v0 + mt * 16 + (lane >> 4) * 4 + j;
                if (vv < VT) {
                    float val = acc[mt][j] + bv;
                    if (vv == VT - 1) val = 0.f;
                    out[((size_t)b * VT + vv) * 3 + lr] = val;
                }
            }
        }
    }
}

extern "C" void kernel_launch(void* const* d_in, const int* in_sizes, int n_in,
                              void* d_out, int out_size, void* d_ws, size_t ws_size,
                              hipStream_t stream) {
    const float* z   = (const float*)d_in[0];
    const float* U0  = (const float*)d_in[1];
    const float* U1  = (const float*)d_in[2];
    const float* U2  = (const float*)d_in[3];
    const int*   S0  = (const int*)d_in[4];
    const int*   S1  = (const int*)d_in[5];
    const int*   S2  = (const int*)d_in[6];
    const float* Wfc = (const float*)d_in[7];
    const float* bfc = (const float*)d_in[8];
    const float* W0  = (const float*)d_in[9];
    const float* b0  = (const float*)d_in[10];
    const float* W1  = (const float*)d_in[11];
    const float* b1  = (const float*)d_in[12];
    const float* W2  = (const float*)d_in[13];
    const float* b2  = (const float*)d_in[14];
    float* out = (float*)d_out;

    char* ws = (char*)d_ws;
    unsigned short* Ub0 = (unsigned short*)(ws + 0);          // [11904][2976]
    unsigned short* Ub1 = (unsigned short*)(ws + 70852608);   // [3072][768]
    unsigned short* Ub2 = (unsigned short*)(ws + 75571200);   // [768][192]
    unsigned short* x3T = (unsigned short*)(ws + 75866112);   // [2048][192]
    unsigned short* x2u = (unsigned short*)(ws + 76652544);   // [16][768][128]
    unsigned short* x2T = (unsigned short*)(ws + 79798272);   // [2048][768]
    unsigned short* x1u = (unsigned short*)(ws + 82944000);   // [16][3072][128]
    unsigned short* x1T = (unsigned short*)(ws + 95526912);   // [1024][3072]
    unsigned short* x0u = (unsigned short*)(ws + 101818368);  // [16][11904][64]
    unsigned short* W0T = (unsigned short*)(ws + 126197760);  // [128][1536]
    unsigned short* W1T = (unsigned short*)(ws + 126590976);  // [64][1792]
    int* S1T = (int*)(ws + 126820352);                        // [14][2949]
    int* S2T = (int*)(ws + 126985504);                        // [12][738]
    int* S0T = (int*)(ws + 127020928);                        // [20][11794]
    unsigned short* W2T = (unsigned short*)(ws + 127964448);  // [16][1288]

    // converters (once per call)
    cvt_ub<<<dim3(12, 11904), 256, 0, stream>>>(U0, Ub0, 11794, 2949, 2976);
    cvt_ub<<<dim3(3, 3072), 256, 0, stream>>>(U1, Ub1, 2949, 738, 768);
    cvt_ub<<<dim3(1, 768), 256, 0, stream>>>(U2, Ub2, 738, 185, 192);
    cvt_wT<<<dim3((128 * 1536 + 255) / 256), 256, 0, stream>>>(W0, W0T, 1536, 128, 128 * 1536);
    cvt_wT<<<dim3((64 * 1792 + 255) / 256), 256, 0, stream>>>(W1, W1T, 1792, 64, 64 * 1792);
    cvt_w2<<<dim3((16 * 1288 + 255) / 256), 256, 0, stream>>>(W2, W2T);
    cvt_sT<<<dim3((14 * 2949 + 255) / 256), 256, 0, stream>>>(S1, S1T, 2949, 14, 14 * 2949);
    cvt_sT<<<dim3((12 * 738 + 255) / 256), 256, 0, stream>>>(S2, S2T, 738, 12, 12 * 738);
    cvt_sT<<<dim3((20 * 11794 + 255) / 256), 256, 0, stream>>>(S0, S0T, 11794, 20, 20 * 11794);
    zero16<<<dim3(192), 256, 0, stream>>>((int4*)x3T, 2048 * 192 * 2 / 16);

    // 1. FC -> x3T
    fc_kernel<<<dim3((185 * 128 + 255) / 256), 256, 0, stream>>>(z, Wfc, bfc, x3T);
    // 2. U2 upsample -> x2u : nsteps=6
    ups_mfma<7, 768><<<dim3(96), 256, 0, stream>>>(Ub2, x3T, x2u, 192, 192, 6, 4, 12);
    // 3. conv0 (K=12,128->128,elu) -> x2T : LDS-free, grid (96,2), M=12288
    conv_nolds<<<dim3(96, 2), 256, 0, stream>>>(x2u, S2T, W0T, b0, x2T, 738, 768, 12, 1536, 128);
    // 4. U1 upsample -> x1u : nsteps=24
    ups_mfma<7, 3072><<<dim3(384), 256, 0, stream>>>(Ub1, x2T, x1u, 768, 768, 24, 4, 48);
    // 5. conv1 (K=14,128->64,elu) -> x1T : LDS-free, grid (384,1), M=49152
    conv_nolds<<<dim3(384, 1), 256, 0, stream>>>(x1u, S1T, W1T, b1, x1T, 2949, 3072, 14, 1792, 64);
    // 6. U0 upsample -> x0u : nsteps=93
    ups_mfma<6, 11904><<<dim3(744), 256, 0, stream>>>(Ub0, x1T, x0u, 2976, 3072, 93, 3, 93);
    // 7. conv2 (K=20, 64->3) LDS-free -> d_out : grid 744, M=190464
    out_nolds<<<dim3(744), 256, 0, stream>>>(x0u, S0T, W2T, b2, out);
}

// Round 11
// 362.921 us; speedup vs baseline: 1.1578x; 1.1578x over previous
//
#include <hip/hip_runtime.h>
#include <cmath>

// Decoder_spirals R10: R8 GEMM structure (proven 375us) + consolidated converters.
// - R9's LDS-free convs REVERTED (regressed +45us: per-lane strided weight-row frag
//   reads = 16 cache lines/instr, no cross-wave reuse; LDS staging wins).
// - cvt_u_all: one kernel for Ub0/Ub1/Ub2; cvt_misc: one kernel for W0T/W1T/W2T/
//   S0T/S1T/S2T; x3T pad-zero folded into fc. 17 -> 9 dispatches.

#define NB 16

typedef __attribute__((ext_vector_type(8))) short bf16x8;
typedef __attribute__((ext_vector_type(4))) float f32x4;

__device__ __forceinline__ unsigned short f2bf(float x) {
    union { float f; unsigned u; } v; v.f = x;
    unsigned r = v.u + 0x7FFFu + ((v.u >> 16) & 1u);
    return (unsigned short)(r >> 16);
}
__device__ __forceinline__ void gload16(const void* src, void* dst) {
    __builtin_amdgcn_global_load_lds(
        (const __attribute__((address_space(1))) unsigned int*)src,
        (__attribute__((address_space(3))) unsigned int*)dst, 16, 0, 0);
}

// ------------- consolidated converters -------------
// All three U matrices fp32 [V][W] -> bf16 [Vp][Wp], zero-padded.
__global__ __launch_bounds__(256) void cvt_u_all(
    const float* __restrict__ U0, const float* __restrict__ U1,
    const float* __restrict__ U2, unsigned short* __restrict__ Ub0,
    unsigned short* __restrict__ Ub1, unsigned short* __restrict__ Ub2) {
    int k = blockIdx.x * 256 + threadIdx.x;
    int r = blockIdx.y;
    const float* src;
    unsigned short* dst;
    int V, W, Wp, row;
    if (r < 11904) {
        src = U0; dst = Ub0; V = 11794; W = 2949; Wp = 2976; row = r;
    } else if (r < 11904 + 3072) {
        src = U1; dst = Ub1; V = 2949; W = 738; Wp = 768; row = r - 11904;
    } else {
        src = U2; dst = Ub2; V = 738; W = 185; Wp = 192; row = r - 11904 - 3072;
    }
    if (k >= Wp) return;
    float v = (row < V && k < W) ? src[(size_t)row * W + k] : 0.f;
    dst[(size_t)row * Wp + k] = f2bf(v);
}

// W0T[128][1536], W1T[64][1792], W2T[16][1288], S0T[20][11794], S1T[14][2949], S2T[12][738]
__global__ __launch_bounds__(256) void cvt_misc(
    const float* __restrict__ W0, const float* __restrict__ W1,
    const float* __restrict__ W2, const int* __restrict__ S0,
    const int* __restrict__ S1, const int* __restrict__ S2,
    unsigned short* __restrict__ W0T, unsigned short* __restrict__ W1T,
    unsigned short* __restrict__ W2T, int* __restrict__ S0T,
    int* __restrict__ S1T, int* __restrict__ S2T) {
    const int N0 = 128 * 1536, N1 = 64 * 1792, N2 = 16 * 1288;
    const int N3 = 20 * 11794, N4 = 14 * 2949, N5 = 12 * 738;
    int id = blockIdx.x * 256 + threadIdx.x;
    if (id < N0) {
        int n = id / 1536, k = id - n * 1536;
        W0T[id] = f2bf(W0[(size_t)k * 128 + n]);
        return;
    }
    id -= N0;
    if (id < N1) {
        int n = id / 1792, k = id - n * 1792;
        W1T[id] = f2bf(W1[(size_t)k * 64 + n]);
        return;
    }
    id -= N1;
    if (id < N2) {
        int n = id / 1288, k = id - n * 1288;
        float v = (n < 3 && k < 1280) ? W2[(size_t)k * 3 + n] : 0.f;
        W2T[id] = f2bf(v);
        return;
    }
    id -= N2;
    if (id < N3) {
        int k = id / 11794, v = id - k * 11794;
        S0T[id] = S0[(size_t)v * 20 + k];
        return;
    }
    id -= N3;
    if (id < N4) {
        int k = id / 2949, v = id - k * 2949;
        S1T[id] = S1[(size_t)v * 14 + k];
        return;
    }
    id -= N4;
    if (id < N5) {
        int k = id / 738, v = id - k * 738;
        S2T[id] = S2[(size_t)v * 12 + k];
    }
}

// -------- FC: z(16,128)@Wfc(128,23680)+bfc -> x3T[b*128+f][192] bf16 (+pad zero) --------
__global__ __launch_bounds__(256) void fc_kernel(const float* __restrict__ z,
                                                 const float* __restrict__ Wfc,
                                                 const float* __restrict__ bfc,
                                                 unsigned short* __restrict__ x3T) {
    const int N = 185 * 128;
    __shared__ float zs[NB * 128];
    int t = threadIdx.x;
    for (int i = t; i < NB * 128; i += 256) zs[i] = z[i];
    __syncthreads();
    int n = blockIdx.x * 256 + t;
    if (n >= N) return;
    float acc[NB];
#pragma unroll
    for (int b = 0; b < NB; ++b) acc[b] = 0.f;
    for (int k = 0; k < 128; ++k) {
        float w = Wfc[k * N + n];
#pragma unroll
        for (int b = 0; b < NB; ++b) acc[b] = fmaf(zs[b * 128 + k], w, acc[b]);
    }
    float bv = bfc[n];
    int f = n & 127, v = n >> 7;
#pragma unroll
    for (int b = 0; b < NB; ++b)
        x3T[(size_t)(b * 128 + f) * 192 + v] = f2bf(acc[b] + bv);
    // pad columns 185..191 (7*128 threads cover them)
    if (n < 7 * 128) {
        int vp = 185 + (n >> 7);
#pragma unroll
        for (int b = 0; b < NB; ++b)
            x3T[(size_t)(b * 128 + f) * 192 + vp] = 0;
    }
}

// ------------- Upsample: out[b,v,f] = sum_w U[v,w]*x[b,w,f] -------------
// 3-buffer, 2-deep prefetch, counted vmcnt(4), unrolled x3 (static buf indices).
template<int FSH, int VP>
__global__ __launch_bounds__(256) void ups_mfma(
    const unsigned short* __restrict__ Ub, const unsigned short* __restrict__ xT,
    unsigned short* __restrict__ out,
    int WpA, int WpB, int nsteps, int gxsh, int q) {
    const int F = 1 << FSH;
    __shared__ __align__(16) unsigned short As[3][128 * 32];
    __shared__ __align__(16) unsigned short Bs[3][128 * 32];
    const int t = threadIdx.x;
    const int wv = t >> 6, lane = t & 63;
    const int lr = lane & 15;

    const int flat = blockIdx.x;
    const int wg = (flat & 7) * q + (flat >> 3);
    const int m0 = (wg >> gxsh) * 128;
    const int n0 = (wg & ((1 << gxsh) - 1)) * 128;

    const int srow = lane >> 2;
    const int schunk = (((lane & 3) - ((lane >> 3) & 3)) & 3) * 8;
    const int ii0 = wv * 2, ii1 = wv * 2 + 1;
    const unsigned short* asrc0 = Ub + (size_t)(m0 + ii0 * 16 + srow) * WpA + schunk;
    const unsigned short* asrc1 = Ub + (size_t)(m0 + ii1 * 16 + srow) * WpA + schunk;
    const unsigned short* bsrc0 = xT + (size_t)(n0 + ii0 * 16 + srow) * WpB + schunk;
    const unsigned short* bsrc1 = xT + (size_t)(n0 + ii1 * 16 + srow) * WpB + schunk;

    const int fslot = (((lane >> 4) + (lr >> 1)) & 3) * 8;
    const int wrow = (wv >> 1) * 64;
    const int wcol = (wv & 1) * 64;
    const int u0 = wv * 1024;

    f32x4 acc[4][4];
#pragma unroll
    for (int i = 0; i < 4; ++i)
#pragma unroll
        for (int j = 0; j < 4; ++j) acc[i][j] = {0.f, 0.f, 0.f, 0.f};

#define UPS_STAGE(off_, B_)                                             \
    {                                                                   \
        gload16(asrc0 + (off_), &As[B_][u0]);                           \
        gload16(bsrc0 + (off_), &Bs[B_][u0]);                           \
        gload16(asrc1 + (off_), &As[B_][u0 + 512]);                     \
        gload16(bsrc1 + (off_), &Bs[B_][u0 + 512]);                     \
    }
#define UPS_COMPUTE(B_)                                                 \
    {                                                                   \
        bf16x8 af[4], bg[4];                                            \
        _Pragma("unroll")                                               \
        for (int mt = 0; mt < 4; ++mt)                                  \
            af[mt] = *(const bf16x8*)&As[B_][(wrow + mt * 16 + lr) * 32 + fslot]; \
        _Pragma("unroll")                                               \
        for (int nt = 0; nt < 4; ++nt)                                  \
            bg[nt] = *(const bf16x8*)&Bs[B_][(wcol + nt * 16 + lr) * 32 + fslot]; \
        _Pragma("unroll")                                               \
        for (int mt = 0; mt < 4; ++mt)                                  \
            _Pragma("unroll")                                           \
            for (int nt = 0; nt < 4; ++nt)                              \
                acc[mt][nt] = __builtin_amdgcn_mfma_f32_16x16x32_bf16(  \
                    af[mt], bg[nt], acc[mt][nt], 0, 0, 0);              \
    }
#define UPS_WAIT4 asm volatile("s_waitcnt vmcnt(4)" ::: "memory"); __builtin_amdgcn_s_barrier();
#define UPS_WAIT0 asm volatile("s_waitcnt vmcnt(0)" ::: "memory"); __builtin_amdgcn_s_barrier();

    UPS_STAGE(0, 0);
    UPS_STAGE(32, 1);
    UPS_WAIT4;

    const int m = nsteps / 3;
    for (int it = 0; it < m - 1; ++it) {
        UPS_STAGE(64, 2);  UPS_COMPUTE(0); UPS_WAIT4;
        UPS_STAGE(96, 0);  UPS_COMPUTE(1); UPS_WAIT4;
        UPS_STAGE(128, 1); UPS_COMPUTE(2); UPS_WAIT4;
        asrc0 += 96; asrc1 += 96; bsrc0 += 96; bsrc1 += 96;
    }
    UPS_STAGE(64, 2);
    UPS_COMPUTE(0); UPS_WAIT4;
    UPS_COMPUTE(1); UPS_WAIT0;
    UPS_COMPUTE(2);
#undef UPS_STAGE
#undef UPS_COMPUTE
#undef UPS_WAIT4
#undef UPS_WAIT0

#pragma unroll
    for (int mt = 0; mt < 4; ++mt) {
        const int vb = m0 + wrow + mt * 16 + (lane >> 4) * 4;
#pragma unroll
        for (int nt = 0; nt < 4; ++nt) {
            const int col = n0 + wcol + nt * 16 + lr;
            const int b = col >> FSH, f = col & (F - 1);
            unsigned short* op = out + (size_t)b * VP * F + f;
#pragma unroll
            for (int j = 0; j < 4; ++j)
                op[(size_t)(vb + j) * F] = f2bf(acc[mt][nt][j]);
        }
    }
}

// ------- SpiralConv: gathered-A bf16 GEMM, 32-row 1-wave tiles, unrolled x2 -------
template<int VP>
__global__ __launch_bounds__(64) void conv_mfma(
    const unsigned short* __restrict__ xu, const int* __restrict__ ST,
    const unsigned short* __restrict__ WT, const float* __restrict__ bias,
    unsigned short* __restrict__ outT,
    int VT, int Ksp, int Kdim, int nsteps, int Fout) {
    __shared__ __align__(16) unsigned short As[2][32 * 32];
    __shared__ __align__(16) unsigned short Bs[2][64 * 32];
    const int lane = threadIdx.x;
    const int lr = lane & 15;
    const int m0 = blockIdx.x * 32;
    const int n0 = blockIdx.y * 64;
    const int b = m0 / VP;
    const int v0 = m0 - b * VP;
    const unsigned short* xb = xu + (((size_t)b * VP) << 7);

    const int arow = lane >> 1;
    const int h = lane & 1;
    const int vg = (v0 + arow < VT) ? (v0 + arow) : (VT - 1);
    const int schunk = (((lane & 3) - ((lane >> 3) & 3)) & 3) * 8;
    const int fslot = (((lane >> 4) + (lr >> 1)) & 3) * 8;
    int sw0 = arow * 32 + (((2 * h + 0 + ((lane >> 2) & 3)) & 3) * 8);
    int sw1 = arow * 32 + (((2 * h + 1 + ((lane >> 2) & 3)) & 3) * 8);

    int s_c = 0;
    int idx_c = ST[vg];
    int idx_n = ST[(size_t)VT + vg];

    f32x4 acc[2][4];
#pragma unroll
    for (int i = 0; i < 2; ++i)
#pragma unroll
        for (int j = 0; j < 4; ++j) acc[i][j] = {0.f, 0.f, 0.f, 0.f};

#define CONV_COMPUTE(B_)                                                \
    {                                                                   \
        bf16x8 af[2], bg[4];                                            \
        _Pragma("unroll")                                               \
        for (int mt = 0; mt < 2; ++mt)                                  \
            af[mt] = *(const bf16x8*)&As[B_][(mt * 16 + lr) * 32 + fslot]; \
        _Pragma("unroll")                                               \
        for (int nt = 0; nt < 4; ++nt)                                  \
            bg[nt] = *(const bf16x8*)&Bs[B_][(nt * 16 + lr) * 32 + fslot]; \
        _Pragma("unroll")                                               \
        for (int mt = 0; mt < 2; ++mt)                                  \
            _Pragma("unroll")                                           \
            for (int nt = 0; nt < 4; ++nt)                              \
                acc[mt][nt] = __builtin_amdgcn_mfma_f32_16x16x32_bf16(  \
                    af[mt], bg[nt], acc[mt][nt], 0, 0, 0);              \
    }
#define CONV_BODY(tn_, CUR_, NXT_)                                      \
    {                                                                   \
        const int k0 = (tn_) * 32;                                      \
        const int sn = k0 >> 7;                                         \
        const int idx = (sn != s_c) ? idx_n : idx_c;                    \
        const unsigned short* p = xb + (((size_t)idx) << 7) + (k0 & 127) + h * 16; \
        bf16x8 g0 = *(const bf16x8*)(p);                                \
        bf16x8 g1 = *(const bf16x8*)(p + 8);                            \
        _Pragma("unroll")                                               \
        for (int i = 0; i < 4; ++i) {                                   \
            const int n = n0 + i * 16 + (lane >> 2);                    \
            gload16(WT + (size_t)n * Kdim + k0 + schunk, &Bs[NXT_][i * 512]); \
        }                                                               \
        if (sn != s_c) {                                                \
            idx_c = idx_n; s_c = sn;                                    \
            if (s_c + 1 < Ksp) idx_n = ST[(size_t)(s_c + 1) * VT + vg]; \
        }                                                               \
        CONV_COMPUTE(CUR_);                                             \
        *(bf16x8*)&As[NXT_][sw0] = g0;                                  \
        *(bf16x8*)&As[NXT_][sw1] = g1;                                  \
        __syncthreads();                                                \
    }

    {
        const unsigned short* p = xb + (((size_t)idx_c) << 7) + h * 16;
        bf16x8 g0 = *(const bf16x8*)(p);
        bf16x8 g1 = *(const bf16x8*)(p + 8);
#pragma unroll
        for (int i = 0; i < 4; ++i) {
            const int n = n0 + i * 16 + (lane >> 2);
            gload16(WT + (size_t)n * Kdim + schunk, &Bs[0][i * 512]);
        }
        *(bf16x8*)&As[0][sw0] = g0;
        *(bf16x8*)&As[0][sw1] = g1;
    }
    __syncthreads();

    for (int ts = 0; ts + 2 < nsteps; ts += 2) {
        CONV_BODY(ts + 1, 0, 1);
        CONV_BODY(ts + 2, 1, 0);
    }
    CONV_BODY(nsteps - 1, 0, 1);
    CONV_COMPUTE(1);
#undef CONV_BODY
#undef CONV_COMPUTE

#pragma unroll
    for (int nt = 0; nt < 4; ++nt) {
        const int n = n0 + nt * 16 + lr;
        const float bv = bias[n];
        unsigned short* op = outT + (size_t)(b * Fout + n) * VP;
#pragma unroll
        for (int mt = 0; mt < 2; ++mt) {
            const int v = v0 + mt * 16 + (lane >> 4) * 4;
            ushort4 stv;
#pragma unroll
            for (int j = 0; j < 4; ++j) {
                float val = acc[mt][nt][j] + bv;
                val = val > 0.f ? val : expm1f(val);
                if (v + j == VT - 1) val = 0.f;
                ((unsigned short*)&stv)[j] = f2bf(val);
            }
            *(ushort4*)(op + v) = stv;
        }
    }
}

// ------- Final conv as MFMA: 32-row 1-wave tiles, N=16 (3 used), K=1280, unrolled x2 -------
__global__ __launch_bounds__(64) void out_mfma(
    const unsigned short* __restrict__ xu, const int* __restrict__ ST,
    const unsigned short* __restrict__ W2T, const float* __restrict__ b2,
    float* __restrict__ out) {
    const int VT = 11794, VP = 11904, TPB = 372;
    __shared__ __align__(16) unsigned short As[2][32 * 32];
    const int lane = threadIdx.x;
    const int lr = lane & 15;
    const int lko = (lane >> 4) * 8;
    const int bm = blockIdx.x;
    const int b = bm / TPB;
    const int v0 = (bm - b * TPB) * 32;
    const unsigned short* xb = xu + ((size_t)b * VP << 6);

    const int arow = lane >> 1;
    const int h = lane & 1;
    const int v = v0 + arow;
    const int vg = v < VT ? v : VT - 1;
    int sw0 = arow * 32 + (((2 * h + 0 + ((lane >> 2) & 3)) & 3) * 8);
    int sw1 = arow * 32 + (((2 * h + 1 + ((lane >> 2) & 3)) & 3) * 8);
    const int fslot = (((lane >> 4) + (lr >> 1)) & 3) * 8;

    int s_c = 0;
    int idx_c = ST[vg];
    int idx_n = ST[VT + vg];

    f32x4 acc[2];
    acc[0] = {0.f, 0.f, 0.f, 0.f};
    acc[1] = {0.f, 0.f, 0.f, 0.f};

    const unsigned short* wrow = W2T + (size_t)lr * 1288 + lko;
    bf16x8 bg_c = *(const bf16x8*)(wrow);

#define OUT_COMPUTE(B_)                                                 \
    {                                                                   \
        bf16x8 af[2];                                                   \
        _Pragma("unroll")                                               \
        for (int mt = 0; mt < 2; ++mt)                                  \
            af[mt] = *(const bf16x8*)&As[B_][(mt * 16 + lr) * 32 + fslot]; \
        _Pragma("unroll")                                               \
        for (int mt = 0; mt < 2; ++mt)                                  \
            acc[mt] = __builtin_amdgcn_mfma_f32_16x16x32_bf16(af[mt], bg_c, acc[mt], 0, 0, 0); \
    }
#define OUT_BODY(tn_, CUR_, NXT_)                                       \
    {                                                                   \
        const int k0 = (tn_) * 32;                                      \
        const int sn = k0 >> 6;                                         \
        const int idx = (sn != s_c) ? idx_n : idx_c;                    \
        const unsigned short* p = xb + (((size_t)idx) << 6) + (k0 & 63) + h * 16; \
        bf16x8 g0 = *(const bf16x8*)(p);                                \
        bf16x8 g1 = *(const bf16x8*)(p + 8);                            \
        bf16x8 bg_n = *(const bf16x8*)(wrow + k0);                      \
        if (sn != s_c) {                                                \
            idx_c = idx_n; s_c = sn;                                    \
            if (s_c + 1 < 20) idx_n = ST[(size_t)(s_c + 1) * VT + vg];  \
        }                                                               \
        OUT_COMPUTE(CUR_);                                              \
        bg_c = bg_n;                                                    \
        *(bf16x8*)&As[NXT_][sw0] = g0;                                  \
        *(bf16x8*)&As[NXT_][sw1] = g1;                                  \
        __syncthreads();                                                \
    }

    {
        const unsigned short* p = xb + ((size_t)idx_c << 6) + h * 16;
        bf16x8 g0 = *(const bf16x8*)(p);
        bf16x8 g1 = *(const bf16x8*)(p + 8);
        *(bf16x8*)&As[0][sw0] = g0;
        *(bf16x8*)&As[0][sw1] = g1;
    }
    __syncthreads();

    const int nsteps = 40;
    for (int ts = 0; ts + 2 < nsteps; ts += 2) {
        OUT_BODY(ts + 1, 0, 1);
        OUT_BODY(ts + 2, 1, 0);
    }
    OUT_BODY(nsteps - 1, 0, 1);
    OUT_COMPUTE(1);
#undef OUT_BODY
#undef OUT_COMPUTE

    if (lr < 3) {
        const float bv = b2[lr];
#pragma unroll
        for (int mt = 0; mt < 2; ++mt) {
#pragma unroll
            for (int j = 0; j < 4; ++j) {
                const int vv = v0 + mt * 16 + (lane >> 4) * 4 + j;
                if (vv < VT) {
                    float val = acc[mt][j] + bv;
                    if (vv == VT - 1) val = 0.f;
                    out[((size_t)b * VT + vv) * 3 + lr] = val;
                }
            }
        }
    }
}

extern "C" void kernel_launch(void* const* d_in, const int* in_sizes, int n_in,
                              void* d_out, int out_size, void* d_ws, size_t ws_size,
                              hipStream_t stream) {
    const float* z   = (const float*)d_in[0];
    const float* U0  = (const float*)d_in[1];
    const float* U1  = (const float*)d_in[2];
    const float* U2  = (const float*)d_in[3];
    const int*   S0  = (const int*)d_in[4];
    const int*   S1  = (const int*)d_in[5];
    const int*   S2  = (const int*)d_in[6];
    const float* Wfc = (const float*)d_in[7];
    const float* bfc = (const float*)d_in[8];
    const float* W0  = (const float*)d_in[9];
    const float* b0  = (const float*)d_in[10];
    const float* W1  = (const float*)d_in[11];
    const float* b1  = (const float*)d_in[12];
    const float* W2  = (const float*)d_in[13];
    const float* b2  = (const float*)d_in[14];
    float* out = (float*)d_out;

    char* ws = (char*)d_ws;
    unsigned short* Ub0 = (unsigned short*)(ws + 0);          // [11904][2976]
    unsigned short* Ub1 = (unsigned short*)(ws + 70852608);   // [3072][768]
    unsigned short* Ub2 = (unsigned short*)(ws + 75571200);   // [768][192]
    unsigned short* x3T = (unsigned short*)(ws + 75866112);   // [2048][192]
    unsigned short* x2u = (unsigned short*)(ws + 76652544);   // [16][768][128]
    unsigned short* x2T = (unsigned short*)(ws + 79798272);   // [2048][768]
    unsigned short* x1u = (unsigned short*)(ws + 82944000);   // [16][3072][128]
    unsigned short* x1T = (unsigned short*)(ws + 95526912);   // [1024][3072]
    unsigned short* x0u = (unsigned short*)(ws + 101818368);  // [16][11904][64]
    unsigned short* W0T = (unsigned short*)(ws + 126197760);  // [128][1536]
    unsigned short* W1T = (unsigned short*)(ws + 126590976);  // [64][1792]
    int* S1T = (int*)(ws + 126820352);                        // [14][2949]
    int* S2T = (int*)(ws + 126985504);                        // [12][738]
    int* S0T = (int*)(ws + 127020928);                        // [20][11794]
    unsigned short* W2T = (unsigned short*)(ws + 127964448);  // [16][1288]

    // consolidated converters (2 dispatches)
    cvt_u_all<<<dim3(12, 11904 + 3072 + 768), 256, 0, stream>>>(U0, U1, U2, Ub0, Ub1, Ub2);
    {
        const int total = 128 * 1536 + 64 * 1792 + 16 * 1288 +
                          20 * 11794 + 14 * 2949 + 12 * 738;
        cvt_misc<<<dim3((total + 255) / 256), 256, 0, stream>>>(
            W0, W1, W2, S0, S1, S2, W0T, W1T, W2T, S0T, S1T, S2T);
    }

    // 1. FC -> x3T (incl. pad-zero)
    fc_kernel<<<dim3((185 * 128 + 255) / 256), 256, 0, stream>>>(z, Wfc, bfc, x3T);
    // 2. U2 upsample -> x2u : nsteps=6
    ups_mfma<7, 768><<<dim3(96), 256, 0, stream>>>(Ub2, x3T, x2u, 192, 192, 6, 4, 12);
    // 3. conv0 (K=12,128->128,elu) -> x2T : 32-row tiles, nsteps=48
    conv_mfma<768><<<dim3(384, 2), 64, 0, stream>>>(x2u, S2T, W0T, b0, x2T, 738, 12, 1536, 48, 128);
    // 4. U1 upsample -> x1u : nsteps=24
    ups_mfma<7, 3072><<<dim3(384), 256, 0, stream>>>(Ub1, x2T, x1u, 768, 768, 24, 4, 48);
    // 5. conv1 (K=14,128->64,elu) -> x1T : 32-row tiles, nsteps=56
    conv_mfma<3072><<<dim3(1536, 1), 64, 0, stream>>>(x1u, S1T, W1T, b1, x1T, 2949, 14, 1792, 56, 64);
    // 6. U0 upsample -> x0u : nsteps=93
    ups_mfma<6, 11904><<<dim3(744), 256, 0, stream>>>(Ub0, x1T, x0u, 2976, 3072, 93, 3, 93);
    // 7. conv2 (K=20, 64->3) as MFMA GEMM -> d_out : 32-row tiles, nsteps=40
    out_mfma<<<dim3(16 * 372), 64, 0, stream>>>(x0u, S0T, W2T, b2, out);
}

// Round 12
// 353.563 us; speedup vs baseline: 1.1884x; 1.0265x over previous
//
#include <hip/hip_runtime.h>
#include <cmath>

// Decoder_spirals R11: barrierless fully-unrolled 1-wave convs.
// - conv_mfma/out_mfma: NO __syncthreads (1-wave blocks don't need it). NSTEPS/KSP
//   template params -> full unroll, all LDS buffer indices constant-folded.
//   Spiral idx preloaded to registers (no index loads in loop). B gload16 2-deep
//   (3 LDS bufs) with one counted vmcnt(4)/step; A gather 1-deep in regs.
//   out_mfma: no gloads at all -> zero waits/barriers.
// - ups/fc/converters unchanged from R10 (U0 at 2-barrier-structure ceiling ~671TF).

#define NB 16

typedef __attribute__((ext_vector_type(8))) short bf16x8;
typedef __attribute__((ext_vector_type(4))) float f32x4;

__device__ __forceinline__ unsigned short f2bf(float x) {
    union { float f; unsigned u; } v; v.f = x;
    unsigned r = v.u + 0x7FFFu + ((v.u >> 16) & 1u);
    return (unsigned short)(r >> 16);
}
__device__ __forceinline__ void gload16(const void* src, void* dst) {
    __builtin_amdgcn_global_load_lds(
        (const __attribute__((address_space(1))) unsigned int*)src,
        (__attribute__((address_space(3))) unsigned int*)dst, 16, 0, 0);
}

// ------------- consolidated converters -------------
__global__ __launch_bounds__(256) void cvt_u_all(
    const float* __restrict__ U0, const float* __restrict__ U1,
    const float* __restrict__ U2, unsigned short* __restrict__ Ub0,
    unsigned short* __restrict__ Ub1, unsigned short* __restrict__ Ub2) {
    int k = blockIdx.x * 256 + threadIdx.x;
    int r = blockIdx.y;
    const float* src;
    unsigned short* dst;
    int V, W, Wp, row;
    if (r < 11904) {
        src = U0; dst = Ub0; V = 11794; W = 2949; Wp = 2976; row = r;
    } else if (r < 11904 + 3072) {
        src = U1; dst = Ub1; V = 2949; W = 738; Wp = 768; row = r - 11904;
    } else {
        src = U2; dst = Ub2; V = 738; W = 185; Wp = 192; row = r - 11904 - 3072;
    }
    if (k >= Wp) return;
    float v = (row < V && k < W) ? src[(size_t)row * W + k] : 0.f;
    dst[(size_t)row * Wp + k] = f2bf(v);
}

__global__ __launch_bounds__(256) void cvt_misc(
    const float* __restrict__ W0, const float* __restrict__ W1,
    const float* __restrict__ W2, const int* __restrict__ S0,
    const int* __restrict__ S1, const int* __restrict__ S2,
    unsigned short* __restrict__ W0T, unsigned short* __restrict__ W1T,
    unsigned short* __restrict__ W2T, int* __restrict__ S0T,
    int* __restrict__ S1T, int* __restrict__ S2T) {
    const int N0 = 128 * 1536, N1 = 64 * 1792, N2 = 16 * 1288;
    const int N3 = 20 * 11794, N4 = 14 * 2949, N5 = 12 * 738;
    int id = blockIdx.x * 256 + threadIdx.x;
    if (id < N0) {
        int n = id / 1536, k = id - n * 1536;
        W0T[id] = f2bf(W0[(size_t)k * 128 + n]);
        return;
    }
    id -= N0;
    if (id < N1) {
        int n = id / 1792, k = id - n * 1792;
        W1T[id] = f2bf(W1[(size_t)k * 64 + n]);
        return;
    }
    id -= N1;
    if (id < N2) {
        int n = id / 1288, k = id - n * 1288;
        float v = (n < 3 && k < 1280) ? W2[(size_t)k * 3 + n] : 0.f;
        W2T[id] = f2bf(v);
        return;
    }
    id -= N2;
    if (id < N3) {
        int k = id / 11794, v = id - k * 11794;
        S0T[id] = S0[(size_t)v * 20 + k];
        return;
    }
    id -= N3;
    if (id < N4) {
        int k = id / 2949, v = id - k * 2949;
        S1T[id] = S1[(size_t)v * 14 + k];
        return;
    }
    id -= N4;
    if (id < N5) {
        int k = id / 738, v = id - k * 738;
        S2T[id] = S2[(size_t)v * 12 + k];
    }
}

// -------- FC: z(16,128)@Wfc(128,23680)+bfc -> x3T[b*128+f][192] bf16 (+pad zero) --------
__global__ __launch_bounds__(256) void fc_kernel(const float* __restrict__ z,
                                                 const float* __restrict__ Wfc,
                                                 const float* __restrict__ bfc,
                                                 unsigned short* __restrict__ x3T) {
    const int N = 185 * 128;
    __shared__ float zs[NB * 128];
    int t = threadIdx.x;
    for (int i = t; i < NB * 128; i += 256) zs[i] = z[i];
    __syncthreads();
    int n = blockIdx.x * 256 + t;
    if (n >= N) return;
    float acc[NB];
#pragma unroll
    for (int b = 0; b < NB; ++b) acc[b] = 0.f;
    for (int k = 0; k < 128; ++k) {
        float w = Wfc[k * N + n];
#pragma unroll
        for (int b = 0; b < NB; ++b) acc[b] = fmaf(zs[b * 128 + k], w, acc[b]);
    }
    float bv = bfc[n];
    int f = n & 127, v = n >> 7;
#pragma unroll
    for (int b = 0; b < NB; ++b)
        x3T[(size_t)(b * 128 + f) * 192 + v] = f2bf(acc[b] + bv);
    if (n < 7 * 128) {
        int vp = 185 + (n >> 7);
#pragma unroll
        for (int b = 0; b < NB; ++b)
            x3T[(size_t)(b * 128 + f) * 192 + vp] = 0;
    }
}

// ------------- Upsample (unchanged from R10) -------------
template<int FSH, int VP>
__global__ __launch_bounds__(256) void ups_mfma(
    const unsigned short* __restrict__ Ub, const unsigned short* __restrict__ xT,
    unsigned short* __restrict__ out,
    int WpA, int WpB, int nsteps, int gxsh, int q) {
    const int F = 1 << FSH;
    __shared__ __align__(16) unsigned short As[3][128 * 32];
    __shared__ __align__(16) unsigned short Bs[3][128 * 32];
    const int t = threadIdx.x;
    const int wv = t >> 6, lane = t & 63;
    const int lr = lane & 15;

    const int flat = blockIdx.x;
    const int wg = (flat & 7) * q + (flat >> 3);
    const int m0 = (wg >> gxsh) * 128;
    const int n0 = (wg & ((1 << gxsh) - 1)) * 128;

    const int srow = lane >> 2;
    const int schunk = (((lane & 3) - ((lane >> 3) & 3)) & 3) * 8;
    const int ii0 = wv * 2, ii1 = wv * 2 + 1;
    const unsigned short* asrc0 = Ub + (size_t)(m0 + ii0 * 16 + srow) * WpA + schunk;
    const unsigned short* asrc1 = Ub + (size_t)(m0 + ii1 * 16 + srow) * WpA + schunk;
    const unsigned short* bsrc0 = xT + (size_t)(n0 + ii0 * 16 + srow) * WpB + schunk;
    const unsigned short* bsrc1 = xT + (size_t)(n0 + ii1 * 16 + srow) * WpB + schunk;

    const int fslot = (((lane >> 4) + (lr >> 1)) & 3) * 8;
    const int wrow = (wv >> 1) * 64;
    const int wcol = (wv & 1) * 64;
    const int u0 = wv * 1024;

    f32x4 acc[4][4];
#pragma unroll
    for (int i = 0; i < 4; ++i)
#pragma unroll
        for (int j = 0; j < 4; ++j) acc[i][j] = {0.f, 0.f, 0.f, 0.f};

#define UPS_STAGE(off_, B_)                                             \
    {                                                                   \
        gload16(asrc0 + (off_), &As[B_][u0]);                           \
        gload16(bsrc0 + (off_), &Bs[B_][u0]);                           \
        gload16(asrc1 + (off_), &As[B_][u0 + 512]);                     \
        gload16(bsrc1 + (off_), &Bs[B_][u0 + 512]);                     \
    }
#define UPS_COMPUTE(B_)                                                 \
    {                                                                   \
        bf16x8 af[4], bg[4];                                            \
        _Pragma("unroll")                                               \
        for (int mt = 0; mt < 4; ++mt)                                  \
            af[mt] = *(const bf16x8*)&As[B_][(wrow + mt * 16 + lr) * 32 + fslot]; \
        _Pragma("unroll")                                               \
        for (int nt = 0; nt < 4; ++nt)                                  \
            bg[nt] = *(const bf16x8*)&Bs[B_][(wcol + nt * 16 + lr) * 32 + fslot]; \
        _Pragma("unroll")                                               \
        for (int mt = 0; mt < 4; ++mt)                                  \
            _Pragma("unroll")                                           \
            for (int nt = 0; nt < 4; ++nt)                              \
                acc[mt][nt] = __builtin_amdgcn_mfma_f32_16x16x32_bf16(  \
                    af[mt], bg[nt], acc[mt][nt], 0, 0, 0);              \
    }
#define UPS_WAIT4 asm volatile("s_waitcnt vmcnt(4)" ::: "memory"); __builtin_amdgcn_s_barrier();
#define UPS_WAIT0 asm volatile("s_waitcnt vmcnt(0)" ::: "memory"); __builtin_amdgcn_s_barrier();

    UPS_STAGE(0, 0);
    UPS_STAGE(32, 1);
    UPS_WAIT4;

    const int m = nsteps / 3;
    for (int it = 0; it < m - 1; ++it) {
        UPS_STAGE(64, 2);  UPS_COMPUTE(0); UPS_WAIT4;
        UPS_STAGE(96, 0);  UPS_COMPUTE(1); UPS_WAIT4;
        UPS_STAGE(128, 1); UPS_COMPUTE(2); UPS_WAIT4;
        asrc0 += 96; asrc1 += 96; bsrc0 += 96; bsrc1 += 96;
    }
    UPS_STAGE(64, 2);
    UPS_COMPUTE(0); UPS_WAIT4;
    UPS_COMPUTE(1); UPS_WAIT0;
    UPS_COMPUTE(2);
#undef UPS_STAGE
#undef UPS_COMPUTE
#undef UPS_WAIT4
#undef UPS_WAIT0

#pragma unroll
    for (int mt = 0; mt < 4; ++mt) {
        const int vb = m0 + wrow + mt * 16 + (lane >> 4) * 4;
#pragma unroll
        for (int nt = 0; nt < 4; ++nt) {
            const int col = n0 + wcol + nt * 16 + lr;
            const int b = col >> FSH, f = col & (F - 1);
            unsigned short* op = out + (size_t)b * VP * F + f;
#pragma unroll
            for (int j = 0; j < 4; ++j)
                op[(size_t)(vb + j) * F] = f2bf(acc[mt][nt][j]);
        }
    }
}

// ------- SpiralConv: barrierless 1-wave 32-row tiles, full unroll, Fin=128 -------
template<int VP, int NSTEPS, int KSP>
__global__ __launch_bounds__(64) void conv_mfma(
    const unsigned short* __restrict__ xu, const int* __restrict__ ST,
    const unsigned short* __restrict__ WT, const float* __restrict__ bias,
    unsigned short* __restrict__ outT,
    int VT, int Kdim, int Fout) {
    __shared__ __align__(16) unsigned short As[2][32 * 32];
    __shared__ __align__(16) unsigned short Bs[3][64 * 32];
    const int lane = threadIdx.x;
    const int lr = lane & 15;
    const int m0 = blockIdx.x * 32;
    const int n0 = blockIdx.y * 64;
    const int b = m0 / VP;
    const int v0 = m0 - b * VP;
    const unsigned short* xb = xu + (((size_t)b * VP) << 7);

    const int arow = lane >> 1;
    const int h = lane & 1;
    const int vg = (v0 + arow < VT) ? (v0 + arow) : (VT - 1);
    const int schunk = (((lane & 3) - ((lane >> 3) & 3)) & 3) * 8;
    const int fslot = (((lane >> 4) + (lr >> 1)) & 3) * 8;
    const int sw0 = arow * 32 + (((2 * h + 0 + ((lane >> 2) & 3)) & 3) * 8);
    const int sw1 = arow * 32 + (((2 * h + 1 + ((lane >> 2) & 3)) & 3) * 8);

    int idx[KSP];
#pragma unroll
    for (int k = 0; k < KSP; ++k) idx[k] = ST[(size_t)k * VT + vg];

    f32x4 acc[2][4];
#pragma unroll
    for (int i = 0; i < 2; ++i)
#pragma unroll
        for (int j = 0; j < 4; ++j) acc[i][j] = {0.f, 0.f, 0.f, 0.f};

    bf16x8 gA[2][2];

#define CC(AB_, BB_)                                                    \
    {                                                                   \
        bf16x8 af[2], bg[4];                                            \
        _Pragma("unroll")                                               \
        for (int mt = 0; mt < 2; ++mt)                                  \
            af[mt] = *(const bf16x8*)&As[AB_][(mt * 16 + lr) * 32 + fslot]; \
        _Pragma("unroll")                                               \
        for (int nt = 0; nt < 4; ++nt)                                  \
            bg[nt] = *(const bf16x8*)&Bs[BB_][(nt * 16 + lr) * 32 + fslot]; \
        _Pragma("unroll")                                               \
        for (int mt = 0; mt < 2; ++mt)                                  \
            _Pragma("unroll")                                           \
            for (int nt = 0; nt < 4; ++nt)                              \
                acc[mt][nt] = __builtin_amdgcn_mfma_f32_16x16x32_bf16(  \
                    af[mt], bg[nt], acc[mt][nt], 0, 0, 0);              \
    }

    // prologue: A(0)->reg->LDS, B(0),B(1) gloads, B(0) waited
    {
        const unsigned short* p = xb + (((size_t)idx[0]) << 7) + h * 16;
        gA[0][0] = *(const bf16x8*)(p);
        gA[0][1] = *(const bf16x8*)(p + 8);
#pragma unroll
        for (int i = 0; i < 4; ++i) {
            const int n = n0 + i * 16 + (lane >> 2);
            gload16(WT + (size_t)n * Kdim + schunk, &Bs[0][i * 512]);
        }
#pragma unroll
        for (int i = 0; i < 4; ++i) {
            const int n = n0 + i * 16 + (lane >> 2);
            gload16(WT + (size_t)n * Kdim + 32 + schunk, &Bs[1][i * 512]);
        }
        *(bf16x8*)&As[0][sw0] = gA[0][0];
        *(bf16x8*)&As[0][sw1] = gA[0][1];
        asm volatile("s_waitcnt vmcnt(4)" ::: "memory");
    }

#pragma unroll
    for (int ts = 0; ts < NSTEPS - 2; ++ts) {
        const int tn1 = ts + 1, tn2 = ts + 2;
        {   // A(tn1) -> regs (1-deep)
            const unsigned short* p =
                xb + (((size_t)idx[tn1 >> 2]) << 7) + (tn1 & 3) * 32 + h * 16;
            gA[tn1 & 1][0] = *(const bf16x8*)(p);
            gA[tn1 & 1][1] = *(const bf16x8*)(p + 8);
        }
        {   // B(tn2) gloads (2-deep)
            const int k0 = tn2 * 32;
#pragma unroll
            for (int i = 0; i < 4; ++i) {
                const int n = n0 + i * 16 + (lane >> 2);
                gload16(WT + (size_t)n * Kdim + k0 + schunk, &Bs[tn2 % 3][i * 512]);
            }
        }
        CC(ts & 1, ts % 3);
        asm volatile("s_waitcnt vmcnt(4)" ::: "memory");  // A(tn1)+B(tn1) done
        *(bf16x8*)&As[tn1 & 1][sw0] = gA[tn1 & 1][0];
        *(bf16x8*)&As[tn1 & 1][sw1] = gA[tn1 & 1][1];
    }
    {   // ts = NSTEPS-2
        const int tn1 = NSTEPS - 1;
        const unsigned short* p =
            xb + (((size_t)idx[tn1 >> 2]) << 7) + (tn1 & 3) * 32 + h * 16;
        gA[tn1 & 1][0] = *(const bf16x8*)(p);
        gA[tn1 & 1][1] = *(const bf16x8*)(p + 8);
        CC((NSTEPS - 2) & 1, (NSTEPS - 2) % 3);
        asm volatile("s_waitcnt vmcnt(0)" ::: "memory");
        *(bf16x8*)&As[tn1 & 1][sw0] = gA[tn1 & 1][0];
        *(bf16x8*)&As[tn1 & 1][sw1] = gA[tn1 & 1][1];
    }
    CC((NSTEPS - 1) & 1, (NSTEPS - 1) % 3);
#undef CC

#pragma unroll
    for (int nt = 0; nt < 4; ++nt) {
        const int n = n0 + nt * 16 + lr;
        const float bv = bias[n];
        unsigned short* op = outT + (size_t)(b * Fout + n) * VP;
#pragma unroll
        for (int mt = 0; mt < 2; ++mt) {
            const int v = v0 + mt * 16 + (lane >> 4) * 4;
            ushort4 stv;
#pragma unroll
            for (int j = 0; j < 4; ++j) {
                float val = acc[mt][nt][j] + bv;
                val = val > 0.f ? val : expm1f(val);
                if (v + j == VT - 1) val = 0.f;
                ((unsigned short*)&stv)[j] = f2bf(val);
            }
            *(ushort4*)(op + v) = stv;
        }
    }
}

// ------- Final conv: barrierless 1-wave 32-row tiles, full unroll, Fin=64, K=1280 -------
__global__ __launch_bounds__(64) void out_mfma(
    const unsigned short* __restrict__ xu, const int* __restrict__ ST,
    const unsigned short* __restrict__ W2T, const float* __restrict__ b2,
    float* __restrict__ out) {
    const int VT = 11794, VP = 11904, TPB = 372, NSTEPS = 40;
    __shared__ __align__(16) unsigned short As[2][32 * 32];
    const int lane = threadIdx.x;
    const int lr = lane & 15;
    const int lko = (lane >> 4) * 8;
    const int bm = blockIdx.x;
    const int b = bm / TPB;
    const int v0 = (bm - b * TPB) * 32;
    const unsigned short* xb = xu + ((size_t)b * VP << 6);

    const int arow = lane >> 1;
    const int h = lane & 1;
    const int v = v0 + arow;
    const int vg = v < VT ? v : VT - 1;
    const int sw0 = arow * 32 + (((2 * h + 0 + ((lane >> 2) & 3)) & 3) * 8);
    const int sw1 = arow * 32 + (((2 * h + 1 + ((lane >> 2) & 3)) & 3) * 8);
    const int fslot = (((lane >> 4) + (lr >> 1)) & 3) * 8;

    int idx[20];
#pragma unroll
    for (int k = 0; k < 20; ++k) idx[k] = ST[(size_t)k * VT + vg];

    f32x4 acc[2];
    acc[0] = {0.f, 0.f, 0.f, 0.f};
    acc[1] = {0.f, 0.f, 0.f, 0.f};

    const unsigned short* wrow = W2T + (size_t)lr * 1288 + lko;
    bf16x8 gA[2][2], bgr[2];

#define OC(AB_, WB_)                                                    \
    {                                                                   \
        bf16x8 af[2];                                                   \
        _Pragma("unroll")                                               \
        for (int mt = 0; mt < 2; ++mt)                                  \
            af[mt] = *(const bf16x8*)&As[AB_][(mt * 16 + lr) * 32 + fslot]; \
        _Pragma("unroll")                                               \
        for (int mt = 0; mt < 2; ++mt)                                  \
            acc[mt] = __builtin_amdgcn_mfma_f32_16x16x32_bf16(          \
                af[mt], bgr[WB_], acc[mt], 0, 0, 0);                    \
    }

    {   // prologue: A(0), B(0)
        const unsigned short* p = xb + (((size_t)idx[0]) << 6) + h * 16;
        gA[0][0] = *(const bf16x8*)(p);
        gA[0][1] = *(const bf16x8*)(p + 8);
        bgr[0] = *(const bf16x8*)(wrow);
        *(bf16x8*)&As[0][sw0] = gA[0][0];
        *(bf16x8*)&As[0][sw1] = gA[0][1];
    }

#pragma unroll
    for (int ts = 0; ts < NSTEPS - 1; ++ts) {
        const int tn = ts + 1;
        const unsigned short* p =
            xb + (((size_t)idx[tn >> 1]) << 6) + (tn & 1) * 32 + h * 16;
        gA[tn & 1][0] = *(const bf16x8*)(p);
        gA[tn & 1][1] = *(const bf16x8*)(p + 8);
        bgr[tn & 1] = *(const bf16x8*)(wrow + tn * 32);
        OC(ts & 1, ts & 1);
        *(bf16x8*)&As[tn & 1][sw0] = gA[tn & 1][0];
        *(bf16x8*)&As[tn & 1][sw1] = gA[tn & 1][1];
    }
    OC((NSTEPS - 1) & 1, (NSTEPS - 1) & 1);
#undef OC

    if (lr < 3) {
        const float bv = b2[lr];
#pragma unroll
        for (int mt = 0; mt < 2; ++mt) {
#pragma unroll
            for (int j = 0; j < 4; ++j) {
                const int vv = v0 + mt * 16 + (lane >> 4) * 4 + j;
                if (vv < VT) {
                    float val = acc[mt][j] + bv;
                    if (vv == VT - 1) val = 0.f;
                    out[((size_t)b * VT + vv) * 3 + lr] = val;
                }
            }
        }
    }
}

extern "C" void kernel_launch(void* const* d_in, const int* in_sizes, int n_in,
                              void* d_out, int out_size, void* d_ws, size_t ws_size,
                              hipStream_t stream) {
    const float* z   = (const float*)d_in[0];
    const float* U0  = (const float*)d_in[1];
    const float* U1  = (const float*)d_in[2];
    const float* U2  = (const float*)d_in[3];
    const int*   S0  = (const int*)d_in[4];
    const int*   S1  = (const int*)d_in[5];
    const int*   S2  = (const int*)d_in[6];
    const float* Wfc = (const float*)d_in[7];
    const float* bfc = (const float*)d_in[8];
    const float* W0  = (const float*)d_in[9];
    const float* b0  = (const float*)d_in[10];
    const float* W1  = (const float*)d_in[11];
    const float* b1  = (const float*)d_in[12];
    const float* W2  = (const float*)d_in[13];
    const float* b2  = (const float*)d_in[14];
    float* out = (float*)d_out;

    char* ws = (char*)d_ws;
    unsigned short* Ub0 = (unsigned short*)(ws + 0);          // [11904][2976]
    unsigned short* Ub1 = (unsigned short*)(ws + 70852608);   // [3072][768]
    unsigned short* Ub2 = (unsigned short*)(ws + 75571200);   // [768][192]
    unsigned short* x3T = (unsigned short*)(ws + 75866112);   // [2048][192]
    unsigned short* x2u = (unsigned short*)(ws + 76652544);   // [16][768][128]
    unsigned short* x2T = (unsigned short*)(ws + 79798272);   // [2048][768]
    unsigned short* x1u = (unsigned short*)(ws + 82944000);   // [16][3072][128]
    unsigned short* x1T = (unsigned short*)(ws + 95526912);   // [1024][3072]
    unsigned short* x0u = (unsigned short*)(ws + 101818368);  // [16][11904][64]
    unsigned short* W0T = (unsigned short*)(ws + 126197760);  // [128][1536]
    unsigned short* W1T = (unsigned short*)(ws + 126590976);  // [64][1792]
    int* S1T = (int*)(ws + 126820352);                        // [14][2949]
    int* S2T = (int*)(ws + 126985504);                        // [12][738]
    int* S0T = (int*)(ws + 127020928);                        // [20][11794]
    unsigned short* W2T = (unsigned short*)(ws + 127964448);  // [16][1288]

    cvt_u_all<<<dim3(12, 11904 + 3072 + 768), 256, 0, stream>>>(U0, U1, U2, Ub0, Ub1, Ub2);
    {
        const int total = 128 * 1536 + 64 * 1792 + 16 * 1288 +
                          20 * 11794 + 14 * 2949 + 12 * 738;
        cvt_misc<<<dim3((total + 255) / 256), 256, 0, stream>>>(
            W0, W1, W2, S0, S1, S2, W0T, W1T, W2T, S0T, S1T, S2T);
    }

    // 1. FC -> x3T (incl. pad-zero)
    fc_kernel<<<dim3((185 * 128 + 255) / 256), 256, 0, stream>>>(z, Wfc, bfc, x3T);
    // 2. U2 upsample -> x2u : nsteps=6
    ups_mfma<7, 768><<<dim3(96), 256, 0, stream>>>(Ub2, x3T, x2u, 192, 192, 6, 4, 12);
    // 3. conv0 (K=12,128->128,elu) -> x2T : barrierless, NSTEPS=48
    conv_mfma<768, 48, 12><<<dim3(384, 2), 64, 0, stream>>>(
        x2u, S2T, W0T, b0, x2T, 738, 1536, 128);
    // 4. U1 upsample -> x1u : nsteps=24
    ups_mfma<7, 3072><<<dim3(384), 256, 0, stream>>>(Ub1, x2T, x1u, 768, 768, 24, 4, 48);
    // 5. conv1 (K=14,128->64,elu) -> x1T : barrierless, NSTEPS=56
    conv_mfma<3072, 56, 14><<<dim3(1536, 1), 64, 0, stream>>>(
        x1u, S1T, W1T, b1, x1T, 2949, 1792, 64);
    // 6. U0 upsample -> x0u : nsteps=93
    ups_mfma<6, 11904><<<dim3(744), 256, 0, stream>>>(Ub0, x1T, x0u, 2976, 3072, 93, 3, 93);
    // 7. conv2 (K=20, 64->3) -> d_out : barrierless, NSTEPS=40
    out_mfma<<<dim3(16 * 372), 64, 0, stream>>>(x0u, S0T, W2T, b2, out);
}

// Round 13
// 342.703 us; speedup vs baseline: 1.2261x; 1.0317x over previous
//
#include <hip/hip_runtime.h>
#include <cmath>

// Decoder_spirals R12:
// - cvt_u_all: flat grid-stride (2048 blocks), 2 elems/thread packed uint writes,
//   compile-time divisors (was 189k tiny blocks with 9/12 dead).
// - ups_mfma: BN 128->64 (wave = 64x32, acc 4x2, 3 gloads/step, vmcnt(3)):
//   U0 grid 744->1488, LDS 36KB -> 4 blocks/CU residency; U1 768, U2 192 blocks.
// - convs/out/fc unchanged from R11 (barrierless full-unroll).

#define NB 16

typedef __attribute__((ext_vector_type(8))) short bf16x8;
typedef __attribute__((ext_vector_type(4))) float f32x4;

__device__ __forceinline__ unsigned short f2bf(float x) {
    union { float f; unsigned u; } v; v.f = x;
    unsigned r = v.u + 0x7FFFu + ((v.u >> 16) & 1u);
    return (unsigned short)(r >> 16);
}
__device__ __forceinline__ void gload16(const void* src, void* dst) {
    __builtin_amdgcn_global_load_lds(
        (const __attribute__((address_space(1))) unsigned int*)src,
        (__attribute__((address_space(3))) unsigned int*)dst, 16, 0, 0);
}

// ------------- consolidated converters -------------
// Grid-stride over element PAIRS; pair never crosses a row (all Wp even).
__global__ __launch_bounds__(256) void cvt_u_all(
    const float* __restrict__ U0, const float* __restrict__ U1,
    const float* __restrict__ U2, unsigned int* __restrict__ Ub0,
    unsigned int* __restrict__ Ub1, unsigned int* __restrict__ Ub2) {
    const unsigned nth = gridDim.x * 256u;
    const unsigned tid = blockIdx.x * 256u + threadIdx.x;
    // U0: [11904][2976] <- [11794][2949], pairs/row = 1488
    for (unsigned p = tid; p < 11904u * 1488u; p += nth) {
        unsigned row = p / 1488u;
        unsigned k = (p - row * 1488u) * 2u;
        float v0 = 0.f, v1 = 0.f;
        if (row < 11794u) {
            const float* s = U0 + (size_t)row * 2949u + k;
            if (k < 2949u) v0 = s[0];
            if (k + 1u < 2949u) v1 = s[1];
        }
        Ub0[p] = (unsigned)f2bf(v0) | ((unsigned)f2bf(v1) << 16);
    }
    // U1: [3072][768] <- [2949][738], pairs/row = 384
    for (unsigned p = tid; p < 3072u * 384u; p += nth) {
        unsigned row = p / 384u;
        unsigned k = (p - row * 384u) * 2u;
        float v0 = 0.f, v1 = 0.f;
        if (row < 2949u) {
            const float* s = U1 + (size_t)row * 738u + k;
            if (k < 738u) v0 = s[0];
            if (k + 1u < 738u) v1 = s[1];
        }
        Ub1[p] = (unsigned)f2bf(v0) | ((unsigned)f2bf(v1) << 16);
    }
    // U2: [768][192] <- [738][185], pairs/row = 96
    for (unsigned p = tid; p < 768u * 96u; p += nth) {
        unsigned row = p / 96u;
        unsigned k = (p - row * 96u) * 2u;
        float v0 = 0.f, v1 = 0.f;
        if (row < 738u) {
            const float* s = U2 + (size_t)row * 185u + k;
            if (k < 185u) v0 = s[0];
            if (k + 1u < 185u) v1 = s[1];
        }
        Ub2[p] = (unsigned)f2bf(v0) | ((unsigned)f2bf(v1) << 16);
    }
}

__global__ __launch_bounds__(256) void cvt_misc(
    const float* __restrict__ W0, const float* __restrict__ W1,
    const float* __restrict__ W2, const int* __restrict__ S0,
    const int* __restrict__ S1, const int* __restrict__ S2,
    unsigned short* __restrict__ W0T, unsigned short* __restrict__ W1T,
    unsigned short* __restrict__ W2T, int* __restrict__ S0T,
    int* __restrict__ S1T, int* __restrict__ S2T) {
    const int N0 = 128 * 1536, N1 = 64 * 1792, N2 = 16 * 1288;
    const int N3 = 20 * 11794, N4 = 14 * 2949, N5 = 12 * 738;
    int id = blockIdx.x * 256 + threadIdx.x;
    if (id < N0) {
        int n = id / 1536, k = id - n * 1536;
        W0T[id] = f2bf(W0[(size_t)k * 128 + n]);
        return;
    }
    id -= N0;
    if (id < N1) {
        int n = id / 1792, k = id - n * 1792;
        W1T[id] = f2bf(W1[(size_t)k * 64 + n]);
        return;
    }
    id -= N1;
    if (id < N2) {
        int n = id / 1288, k = id - n * 1288;
        float v = (n < 3 && k < 1280) ? W2[(size_t)k * 3 + n] : 0.f;
        W2T[id] = f2bf(v);
        return;
    }
    id -= N2;
    if (id < N3) {
        int k = id / 11794, v = id - k * 11794;
        S0T[id] = S0[(size_t)v * 20 + k];
        return;
    }
    id -= N3;
    if (id < N4) {
        int k = id / 2949, v = id - k * 2949;
        S1T[id] = S1[(size_t)v * 14 + k];
        return;
    }
    id -= N4;
    if (id < N5) {
        int k = id / 738, v = id - k * 738;
        S2T[id] = S2[(size_t)v * 12 + k];
    }
}

// -------- FC: z(16,128)@Wfc(128,23680)+bfc -> x3T[b*128+f][192] bf16 (+pad zero) --------
__global__ __launch_bounds__(256) void fc_kernel(const float* __restrict__ z,
                                                 const float* __restrict__ Wfc,
                                                 const float* __restrict__ bfc,
                                                 unsigned short* __restrict__ x3T) {
    const int N = 185 * 128;
    __shared__ float zs[NB * 128];
    int t = threadIdx.x;
    for (int i = t; i < NB * 128; i += 256) zs[i] = z[i];
    __syncthreads();
    int n = blockIdx.x * 256 + t;
    if (n >= N) return;
    float acc[NB];
#pragma unroll
    for (int b = 0; b < NB; ++b) acc[b] = 0.f;
    for (int k = 0; k < 128; ++k) {
        float w = Wfc[k * N + n];
#pragma unroll
        for (int b = 0; b < NB; ++b) acc[b] = fmaf(zs[b * 128 + k], w, acc[b]);
    }
    float bv = bfc[n];
    int f = n & 127, v = n >> 7;
#pragma unroll
    for (int b = 0; b < NB; ++b)
        x3T[(size_t)(b * 128 + f) * 192 + v] = f2bf(acc[b] + bv);
    if (n < 7 * 128) {
        int vp = 185 + (n >> 7);
#pragma unroll
        for (int b = 0; b < NB; ++b)
            x3T[(size_t)(b * 128 + f) * 192 + vp] = 0;
    }
}

// ------------- Upsample: BM=128, BN=64; wave = 64x32 (acc 4x2); 3-buf vmcnt(3) -------------
template<int FSH, int VP>
__global__ __launch_bounds__(256) void ups_mfma(
    const unsigned short* __restrict__ Ub, const unsigned short* __restrict__ xT,
    unsigned short* __restrict__ out,
    int WpA, int WpB, int nsteps, int gxsh, int q) {
    const int F = 1 << FSH;
    __shared__ __align__(16) unsigned short As[3][128 * 32];
    __shared__ __align__(16) unsigned short Bs[3][64 * 32];
    const int t = threadIdx.x;
    const int wv = t >> 6, lane = t & 63;
    const int lr = lane & 15;

    const int flat = blockIdx.x;
    const int wg = (flat & 7) * q + (flat >> 3);
    const int m0 = (wg >> gxsh) * 128;
    const int n0 = (wg & ((1 << gxsh) - 1)) * 64;

    const int srow = lane >> 2;
    const int schunk = (((lane & 3) - ((lane >> 3) & 3)) & 3) * 8;
    const int ii0 = wv * 2, ii1 = wv * 2 + 1;
    const unsigned short* asrc0 = Ub + (size_t)(m0 + ii0 * 16 + srow) * WpA + schunk;
    const unsigned short* asrc1 = Ub + (size_t)(m0 + ii1 * 16 + srow) * WpA + schunk;
    const unsigned short* bsrc0 = xT + (size_t)(n0 + wv * 16 + srow) * WpB + schunk;

    const int fslot = (((lane >> 4) + (lr >> 1)) & 3) * 8;
    const int wrow = (wv >> 1) * 64;
    const int wcol = (wv & 1) * 32;
    const int u0 = wv * 1024;
    const int ub0 = wv * 512;

    f32x4 acc[4][2];
#pragma unroll
    for (int i = 0; i < 4; ++i)
#pragma unroll
        for (int j = 0; j < 2; ++j) acc[i][j] = {0.f, 0.f, 0.f, 0.f};

#define UPS_STAGE(off_, B_)                                             \
    {                                                                   \
        gload16(asrc0 + (off_), &As[B_][u0]);                           \
        gload16(bsrc0 + (off_), &Bs[B_][ub0]);                          \
        gload16(asrc1 + (off_), &As[B_][u0 + 512]);                     \
    }
#define UPS_COMPUTE(B_)                                                 \
    {                                                                   \
        bf16x8 af[4], bg[2];                                            \
        _Pragma("unroll")                                               \
        for (int mt = 0; mt < 4; ++mt)                                  \
            af[mt] = *(const bf16x8*)&As[B_][(wrow + mt * 16 + lr) * 32 + fslot]; \
        _Pragma("unroll")                                               \
        for (int nt = 0; nt < 2; ++nt)                                  \
            bg[nt] = *(const bf16x8*)&Bs[B_][(wcol + nt * 16 + lr) * 32 + fslot]; \
        _Pragma("unroll")                                               \
        for (int mt = 0; mt < 4; ++mt)                                  \
            _Pragma("unroll")                                           \
            for (int nt = 0; nt < 2; ++nt)                              \
                acc[mt][nt] = __builtin_amdgcn_mfma_f32_16x16x32_bf16(  \
                    af[mt], bg[nt], acc[mt][nt], 0, 0, 0);              \
    }
#define UPS_WAIT3 asm volatile("s_waitcnt vmcnt(3)" ::: "memory"); __builtin_amdgcn_s_barrier();
#define UPS_WAIT0 asm volatile("s_waitcnt vmcnt(0)" ::: "memory"); __builtin_amdgcn_s_barrier();

    UPS_STAGE(0, 0);
    UPS_STAGE(32, 1);
    UPS_WAIT3;

    const int m = nsteps / 3;
    for (int it = 0; it < m - 1; ++it) {
        UPS_STAGE(64, 2);  UPS_COMPUTE(0); UPS_WAIT3;
        UPS_STAGE(96, 0);  UPS_COMPUTE(1); UPS_WAIT3;
        UPS_STAGE(128, 1); UPS_COMPUTE(2); UPS_WAIT3;
        asrc0 += 96; asrc1 += 96; bsrc0 += 96;
    }
    UPS_STAGE(64, 2);
    UPS_COMPUTE(0); UPS_WAIT3;
    UPS_COMPUTE(1); UPS_WAIT0;
    UPS_COMPUTE(2);
#undef UPS_STAGE
#undef UPS_COMPUTE
#undef UPS_WAIT3
#undef UPS_WAIT0

#pragma unroll
    for (int mt = 0; mt < 4; ++mt) {
        const int vb = m0 + wrow + mt * 16 + (lane >> 4) * 4;
#pragma unroll
        for (int nt = 0; nt < 2; ++nt) {
            const int col = n0 + wcol + nt * 16 + lr;
            const int b = col >> FSH, f = col & (F - 1);
            unsigned short* op = out + (size_t)b * VP * F + f;
#pragma unroll
            for (int j = 0; j < 4; ++j)
                op[(size_t)(vb + j) * F] = f2bf(acc[mt][nt][j]);
        }
    }
}

// ------- SpiralConv: barrierless 1-wave 32-row tiles, full unroll, Fin=128 -------
template<int VP, int NSTEPS, int KSP>
__global__ __launch_bounds__(64) void conv_mfma(
    const unsigned short* __restrict__ xu, const int* __restrict__ ST,
    const unsigned short* __restrict__ WT, const float* __restrict__ bias,
    unsigned short* __restrict__ outT,
    int VT, int Kdim, int Fout) {
    __shared__ __align__(16) unsigned short As[2][32 * 32];
    __shared__ __align__(16) unsigned short Bs[3][64 * 32];
    const int lane = threadIdx.x;
    const int lr = lane & 15;
    const int m0 = blockIdx.x * 32;
    const int n0 = blockIdx.y * 64;
    const int b = m0 / VP;
    const int v0 = m0 - b * VP;
    const unsigned short* xb = xu + (((size_t)b * VP) << 7);

    const int arow = lane >> 1;
    const int h = lane & 1;
    const int vg = (v0 + arow < VT) ? (v0 + arow) : (VT - 1);
    const int schunk = (((lane & 3) - ((lane >> 3) & 3)) & 3) * 8;
    const int fslot = (((lane >> 4) + (lr >> 1)) & 3) * 8;
    const int sw0 = arow * 32 + (((2 * h + 0 + ((lane >> 2) & 3)) & 3) * 8);
    const int sw1 = arow * 32 + (((2 * h + 1 + ((lane >> 2) & 3)) & 3) * 8);

    int idx[KSP];
#pragma unroll
    for (int k = 0; k < KSP; ++k) idx[k] = ST[(size_t)k * VT + vg];

    f32x4 acc[2][4];
#pragma unroll
    for (int i = 0; i < 2; ++i)
#pragma unroll
        for (int j = 0; j < 4; ++j) acc[i][j] = {0.f, 0.f, 0.f, 0.f};

    bf16x8 gA[2][2];

#define CC(AB_, BB_)                                                    \
    {                                                                   \
        bf16x8 af[2], bg[4];                                            \
        _Pragma("unroll")                                               \
        for (int mt = 0; mt < 2; ++mt)                                  \
            af[mt] = *(const bf16x8*)&As[AB_][(mt * 16 + lr) * 32 + fslot]; \
        _Pragma("unroll")                                               \
        for (int nt = 0; nt < 4; ++nt)                                  \
            bg[nt] = *(const bf16x8*)&Bs[BB_][(nt * 16 + lr) * 32 + fslot]; \
        _Pragma("unroll")                                               \
        for (int mt = 0; mt < 2; ++mt)                                  \
            _Pragma("unroll")                                           \
            for (int nt = 0; nt < 4; ++nt)                              \
                acc[mt][nt] = __builtin_amdgcn_mfma_f32_16x16x32_bf16(  \
                    af[mt], bg[nt], acc[mt][nt], 0, 0, 0);              \
    }

    {
        const unsigned short* p = xb + (((size_t)idx[0]) << 7) + h * 16;
        gA[0][0] = *(const bf16x8*)(p);
        gA[0][1] = *(const bf16x8*)(p + 8);
#pragma unroll
        for (int i = 0; i < 4; ++i) {
            const int n = n0 + i * 16 + (lane >> 2);
            gload16(WT + (size_t)n * Kdim + schunk, &Bs[0][i * 512]);
        }
#pragma unroll
        for (int i = 0; i < 4; ++i) {
            const int n = n0 + i * 16 + (lane >> 2);
            gload16(WT + (size_t)n * Kdim + 32 + schunk, &Bs[1][i * 512]);
        }
        *(bf16x8*)&As[0][sw0] = gA[0][0];
        *(bf16x8*)&As[0][sw1] = gA[0][1];
        asm volatile("s_waitcnt vmcnt(4)" ::: "memory");
    }

#pragma unroll
    for (int ts = 0; ts < NSTEPS - 2; ++ts) {
        const int tn1 = ts + 1, tn2 = ts + 2;
        {
            const unsigned short* p =
                xb + (((size_t)idx[tn1 >> 2]) << 7) + (tn1 & 3) * 32 + h * 16;
            gA[tn1 & 1][0] = *(const bf16x8*)(p);
            gA[tn1 & 1][1] = *(const bf16x8*)(p + 8);
        }
        {
            const int k0 = tn2 * 32;
#pragma unroll
            for (int i = 0; i < 4; ++i) {
                const int n = n0 + i * 16 + (lane >> 2);
                gload16(WT + (size_t)n * Kdim + k0 + schunk, &Bs[tn2 % 3][i * 512]);
            }
        }
        CC(ts & 1, ts % 3);
        asm volatile("s_waitcnt vmcnt(4)" ::: "memory");
        *(bf16x8*)&As[tn1 & 1][sw0] = gA[tn1 & 1][0];
        *(bf16x8*)&As[tn1 & 1][sw1] = gA[tn1 & 1][1];
    }
    {
        const int tn1 = NSTEPS - 1;
        const unsigned short* p =
            xb + (((size_t)idx[tn1 >> 2]) << 7) + (tn1 & 3) * 32 + h * 16;
        gA[tn1 & 1][0] = *(const bf16x8*)(p);
        gA[tn1 & 1][1] = *(const bf16x8*)(p + 8);
        CC((NSTEPS - 2) & 1, (NSTEPS - 2) % 3);
        asm volatile("s_waitcnt vmcnt(0)" ::: "memory");
        *(bf16x8*)&As[tn1 & 1][sw0] = gA[tn1 & 1][0];
        *(bf16x8*)&As[tn1 & 1][sw1] = gA[tn1 & 1][1];
    }
    CC((NSTEPS - 1) & 1, (NSTEPS - 1) % 3);
#undef CC

#pragma unroll
    for (int nt = 0; nt < 4; ++nt) {
        const int n = n0 + nt * 16 + lr;
        const float bv = bias[n];
        unsigned short* op = outT + (size_t)(b * Fout + n) * VP;
#pragma unroll
        for (int mt = 0; mt < 2; ++mt) {
            const int v = v0 + mt * 16 + (lane >> 4) * 4;
            ushort4 stv;
#pragma unroll
            for (int j = 0; j < 4; ++j) {
                float val = acc[mt][nt][j] + bv;
                val = val > 0.f ? val : expm1f(val);
                if (v + j == VT - 1) val = 0.f;
                ((unsigned short*)&stv)[j] = f2bf(val);
            }
            *(ushort4*)(op + v) = stv;
        }
    }
}

// ------- Final conv: barrierless 1-wave 32-row tiles, full unroll, Fin=64, K=1280 -------
__global__ __launch_bounds__(64) void out_mfma(
    const unsigned short* __restrict__ xu, const int* __restrict__ ST,
    const unsigned short* __restrict__ W2T, const float* __restrict__ b2,
    float* __restrict__ out) {
    const int VT = 11794, VP = 11904, TPB = 372, NSTEPS = 40;
    __shared__ __align__(16) unsigned short As[2][32 * 32];
    const int lane = threadIdx.x;
    const int lr = lane & 15;
    const int lko = (lane >> 4) * 8;
    const int bm = blockIdx.x;
    const int b = bm / TPB;
    const int v0 = (bm - b * TPB) * 32;
    const unsigned short* xb = xu + ((size_t)b * VP << 6);

    const int arow = lane >> 1;
    const int h = lane & 1;
    const int v = v0 + arow;
    const int vg = v < VT ? v : VT - 1;
    const int sw0 = arow * 32 + (((2 * h + 0 + ((lane >> 2) & 3)) & 3) * 8);
    const int sw1 = arow * 32 + (((2 * h + 1 + ((lane >> 2) & 3)) & 3) * 8);
    const int fslot = (((lane >> 4) + (lr >> 1)) & 3) * 8;

    int idx[20];
#pragma unroll
    for (int k = 0; k < 20; ++k) idx[k] = ST[(size_t)k * VT + vg];

    f32x4 acc[2];
    acc[0] = {0.f, 0.f, 0.f, 0.f};
    acc[1] = {0.f, 0.f, 0.f, 0.f};

    const unsigned short* wrow = W2T + (size_t)lr * 1288 + lko;
    bf16x8 gA[2][2], bgr[2];

#define OC(AB_, WB_)                                                    \
    {                                                                   \
        bf16x8 af[2];                                                   \
        _Pragma("unroll")                                               \
        for (int mt = 0; mt < 2; ++mt)                                  \
            af[mt] = *(const bf16x8*)&As[AB_][(mt * 16 + lr) * 32 + fslot]; \
        _Pragma("unroll")                                               \
        for (int mt = 0; mt < 2; ++mt)                                  \
            acc[mt] = __builtin_amdgcn_mfma_f32_16x16x32_bf16(          \
                af[mt], bgr[WB_], acc[mt], 0, 0, 0);                    \
    }

    {
        const unsigned short* p = xb + (((size_t)idx[0]) << 6) + h * 16;
        gA[0][0] = *(const bf16x8*)(p);
        gA[0][1] = *(const bf16x8*)(p + 8);
        bgr[0] = *(const bf16x8*)(wrow);
        *(bf16x8*)&As[0][sw0] = gA[0][0];
        *(bf16x8*)&As[0][sw1] = gA[0][1];
    }

#pragma unroll
    for (int ts = 0; ts < NSTEPS - 1; ++ts) {
        const int tn = ts + 1;
        const unsigned short* p =
            xb + (((size_t)idx[tn >> 1]) << 6) + (tn & 1) * 32 + h * 16;
        gA[tn & 1][0] = *(const bf16x8*)(p);
        gA[tn & 1][1] = *(const bf16x8*)(p + 8);
        bgr[tn & 1] = *(const bf16x8*)(wrow + tn * 32);
        OC(ts & 1, ts & 1);
        *(bf16x8*)&As[tn & 1][sw0] = gA[tn & 1][0];
        *(bf16x8*)&As[tn & 1][sw1] = gA[tn & 1][1];
    }
    OC((NSTEPS - 1) & 1, (NSTEPS - 1) & 1);
#undef OC

    if (lr < 3) {
        const float bv = b2[lr];
#pragma unroll
        for (int mt = 0; mt < 2; ++mt) {
#pragma unroll
            for (int j = 0; j < 4; ++j) {
                const int vv = v0 + mt * 16 + (lane >> 4) * 4 + j;
                if (vv < VT) {
                    float val = acc[mt][j] + bv;
                    if (vv == VT - 1) val = 0.f;
                    out[((size_t)b * VT + vv) * 3 + lr] = val;
                }
            }
        }
    }
}

extern "C" void kernel_launch(void* const* d_in, const int* in_sizes, int n_in,
                              void* d_out, int out_size, void* d_ws, size_t ws_size,
                              hipStream_t stream) {
    const float* z   = (const float*)d_in[0];
    const float* U0  = (const float*)d_in[1];
    const float* U1  = (const float*)d_in[2];
    const float* U2  = (const float*)d_in[3];
    const int*   S0  = (const int*)d_in[4];
    const int*   S1  = (const int*)d_in[5];
    const int*   S2  = (const int*)d_in[6];
    const float* Wfc = (const float*)d_in[7];
    const float* bfc = (const float*)d_in[8];
    const float* W0  = (const float*)d_in[9];
    const float* b0  = (const float*)d_in[10];
    const float* W1  = (const float*)d_in[11];
    const float* b1  = (const float*)d_in[12];
    const float* W2  = (const float*)d_in[13];
    const float* b2  = (const float*)d_in[14];
    float* out = (float*)d_out;

    char* ws = (char*)d_ws;
    unsigned short* Ub0 = (unsigned short*)(ws + 0);          // [11904][2976]
    unsigned short* Ub1 = (unsigned short*)(ws + 70852608);   // [3072][768]
    unsigned short* Ub2 = (unsigned short*)(ws + 75571200);   // [768][192]
    unsigned short* x3T = (unsigned short*)(ws + 75866112);   // [2048][192]
    unsigned short* x2u = (unsigned short*)(ws + 76652544);   // [16][768][128]
    unsigned short* x2T = (unsigned short*)(ws + 79798272);   // [2048][768]
    unsigned short* x1u = (unsigned short*)(ws + 82944000);   // [16][3072][128]
    unsigned short* x1T = (unsigned short*)(ws + 95526912);   // [1024][3072]
    unsigned short* x0u = (unsigned short*)(ws + 101818368);  // [16][11904][64]
    unsigned short* W0T = (unsigned short*)(ws + 126197760);  // [128][1536]
    unsigned short* W1T = (unsigned short*)(ws + 126590976);  // [64][1792]
    int* S1T = (int*)(ws + 126820352);                        // [14][2949]
    int* S2T = (int*)(ws + 126985504);                        // [12][738]
    int* S0T = (int*)(ws + 127020928);                        // [20][11794]
    unsigned short* W2T = (unsigned short*)(ws + 127964448);  // [16][1288]

    cvt_u_all<<<dim3(2048), 256, 0, stream>>>(U0, U1, U2,
        (unsigned int*)Ub0, (unsigned int*)Ub1, (unsigned int*)Ub2);
    {
        const int total = 128 * 1536 + 64 * 1792 + 16 * 1288 +
                          20 * 11794 + 14 * 2949 + 12 * 738;
        cvt_misc<<<dim3((total + 255) / 256), 256, 0, stream>>>(
            W0, W1, W2, S0, S1, S2, W0T, W1T, W2T, S0T, S1T, S2T);
    }

    // 1. FC -> x3T (incl. pad-zero)
    fc_kernel<<<dim3((185 * 128 + 255) / 256), 256, 0, stream>>>(z, Wfc, bfc, x3T);
    // 2. U2 upsample -> x2u : BM128/BN64, grid 6*32=192, q=24, nsteps=6
    ups_mfma<7, 768><<<dim3(192), 256, 0, stream>>>(Ub2, x3T, x2u, 192, 192, 6, 5, 24);
    // 3. conv0 (K=12,128->128,elu) -> x2T : barrierless, NSTEPS=48
    conv_mfma<768, 48, 12><<<dim3(384, 2), 64, 0, stream>>>(
        x2u, S2T, W0T, b0, x2T, 738, 1536, 128);
    // 4. U1 upsample -> x1u : grid 24*32=768, q=96, nsteps=24
    ups_mfma<7, 3072><<<dim3(768), 256, 0, stream>>>(Ub1, x2T, x1u, 768, 768, 24, 5, 96);
    // 5. conv1 (K=14,128->64,elu) -> x1T : barrierless, NSTEPS=56
    conv_mfma<3072, 56, 14><<<dim3(1536, 1), 64, 0, stream>>>(
        x1u, S1T, W1T, b1, x1T, 2949, 1792, 64);
    // 6. U0 upsample -> x0u : grid 93*16=1488, q=186, nsteps=93
    ups_mfma<6, 11904><<<dim3(1488), 256, 0, stream>>>(Ub0, x1T, x0u, 2976, 3072, 93, 4, 186);
    // 7. conv2 (K=20, 64->3) -> d_out : barrierless, NSTEPS=40
    out_mfma<<<dim3(16 * 372), 64, 0, stream>>>(x0u, S0T, W2T, b2, out);
}

// Round 14
// 309.237 us; speedup vs baseline: 1.3588x; 1.1082x over previous
//
#include <hip/hip_runtime.h>
#include <cmath>

// Decoder_spirals R13: R11 ups (BN=128, proven 111us U0) + R12 cvt_u_all (grid-stride).
// R12's BN=64 ups REVERTED: halved MFMA-per-staged-byte + doubled A re-fetch ->
// U0 143us (vs 103). Convs/out/fc unchanged (barrierless full-unroll).

#define NB 16

typedef __attribute__((ext_vector_type(8))) short bf16x8;
typedef __attribute__((ext_vector_type(4))) float f32x4;

__device__ __forceinline__ unsigned short f2bf(float x) {
    union { float f; unsigned u; } v; v.f = x;
    unsigned r = v.u + 0x7FFFu + ((v.u >> 16) & 1u);
    return (unsigned short)(r >> 16);
}
__device__ __forceinline__ void gload16(const void* src, void* dst) {
    __builtin_amdgcn_global_load_lds(
        (const __attribute__((address_space(1))) unsigned int*)src,
        (__attribute__((address_space(3))) unsigned int*)dst, 16, 0, 0);
}

// ------------- consolidated converters -------------
__global__ __launch_bounds__(256) void cvt_u_all(
    const float* __restrict__ U0, const float* __restrict__ U1,
    const float* __restrict__ U2, unsigned int* __restrict__ Ub0,
    unsigned int* __restrict__ Ub1, unsigned int* __restrict__ Ub2) {
    const unsigned nth = gridDim.x * 256u;
    const unsigned tid = blockIdx.x * 256u + threadIdx.x;
    for (unsigned p = tid; p < 11904u * 1488u; p += nth) {
        unsigned row = p / 1488u;
        unsigned k = (p - row * 1488u) * 2u;
        float v0 = 0.f, v1 = 0.f;
        if (row < 11794u) {
            const float* s = U0 + (size_t)row * 2949u + k;
            if (k < 2949u) v0 = s[0];
            if (k + 1u < 2949u) v1 = s[1];
        }
        Ub0[p] = (unsigned)f2bf(v0) | ((unsigned)f2bf(v1) << 16);
    }
    for (unsigned p = tid; p < 3072u * 384u; p += nth) {
        unsigned row = p / 384u;
        unsigned k = (p - row * 384u) * 2u;
        float v0 = 0.f, v1 = 0.f;
        if (row < 2949u) {
            const float* s = U1 + (size_t)row * 738u + k;
            if (k < 738u) v0 = s[0];
            if (k + 1u < 738u) v1 = s[1];
        }
        Ub1[p] = (unsigned)f2bf(v0) | ((unsigned)f2bf(v1) << 16);
    }
    for (unsigned p = tid; p < 768u * 96u; p += nth) {
        unsigned row = p / 96u;
        unsigned k = (p - row * 96u) * 2u;
        float v0 = 0.f, v1 = 0.f;
        if (row < 738u) {
            const float* s = U2 + (size_t)row * 185u + k;
            if (k < 185u) v0 = s[0];
            if (k + 1u < 185u) v1 = s[1];
        }
        Ub2[p] = (unsigned)f2bf(v0) | ((unsigned)f2bf(v1) << 16);
    }
}

__global__ __launch_bounds__(256) void cvt_misc(
    const float* __restrict__ W0, const float* __restrict__ W1,
    const float* __restrict__ W2, const int* __restrict__ S0,
    const int* __restrict__ S1, const int* __restrict__ S2,
    unsigned short* __restrict__ W0T, unsigned short* __restrict__ W1T,
    unsigned short* __restrict__ W2T, int* __restrict__ S0T,
    int* __restrict__ S1T, int* __restrict__ S2T) {
    const int N0 = 128 * 1536, N1 = 64 * 1792, N2 = 16 * 1288;
    const int N3 = 20 * 11794, N4 = 14 * 2949, N5 = 12 * 738;
    int id = blockIdx.x * 256 + threadIdx.x;
    if (id < N0) {
        int n = id / 1536, k = id - n * 1536;
        W0T[id] = f2bf(W0[(size_t)k * 128 + n]);
        return;
    }
    id -= N0;
    if (id < N1) {
        int n = id / 1792, k = id - n * 1792;
        W1T[id] = f2bf(W1[(size_t)k * 64 + n]);
        return;
    }
    id -= N1;
    if (id < N2) {
        int n = id / 1288, k = id - n * 1288;
        float v = (n < 3 && k < 1280) ? W2[(size_t)k * 3 + n] : 0.f;
        W2T[id] = f2bf(v);
        return;
    }
    id -= N2;
    if (id < N3) {
        int k = id / 11794, v = id - k * 11794;
        S0T[id] = S0[(size_t)v * 20 + k];
        return;
    }
    id -= N3;
    if (id < N4) {
        int k = id / 2949, v = id - k * 2949;
        S1T[id] = S1[(size_t)v * 14 + k];
        return;
    }
    id -= N4;
    if (id < N5) {
        int k = id / 738, v = id - k * 738;
        S2T[id] = S2[(size_t)v * 12 + k];
    }
}

// -------- FC: z(16,128)@Wfc(128,23680)+bfc -> x3T[b*128+f][192] bf16 (+pad zero) --------
__global__ __launch_bounds__(256) void fc_kernel(const float* __restrict__ z,
                                                 const float* __restrict__ Wfc,
                                                 const float* __restrict__ bfc,
                                                 unsigned short* __restrict__ x3T) {
    const int N = 185 * 128;
    __shared__ float zs[NB * 128];
    int t = threadIdx.x;
    for (int i = t; i < NB * 128; i += 256) zs[i] = z[i];
    __syncthreads();
    int n = blockIdx.x * 256 + t;
    if (n >= N) return;
    float acc[NB];
#pragma unroll
    for (int b = 0; b < NB; ++b) acc[b] = 0.f;
    for (int k = 0; k < 128; ++k) {
        float w = Wfc[k * N + n];
#pragma unroll
        for (int b = 0; b < NB; ++b) acc[b] = fmaf(zs[b * 128 + k], w, acc[b]);
    }
    float bv = bfc[n];
    int f = n & 127, v = n >> 7;
#pragma unroll
    for (int b = 0; b < NB; ++b)
        x3T[(size_t)(b * 128 + f) * 192 + v] = f2bf(acc[b] + bv);
    if (n < 7 * 128) {
        int vp = 185 + (n >> 7);
#pragma unroll
        for (int b = 0; b < NB; ++b)
            x3T[(size_t)(b * 128 + f) * 192 + vp] = 0;
    }
}

// ------------- Upsample: BM=BN=128, wave=64x64; 3-buf, 2-deep, vmcnt(4) -------------
template<int FSH, int VP>
__global__ __launch_bounds__(256) void ups_mfma(
    const unsigned short* __restrict__ Ub, const unsigned short* __restrict__ xT,
    unsigned short* __restrict__ out,
    int WpA, int WpB, int nsteps, int gxsh, int q) {
    const int F = 1 << FSH;
    __shared__ __align__(16) unsigned short As[3][128 * 32];
    __shared__ __align__(16) unsigned short Bs[3][128 * 32];
    const int t = threadIdx.x;
    const int wv = t >> 6, lane = t & 63;
    const int lr = lane & 15;

    const int flat = blockIdx.x;
    const int wg = (flat & 7) * q + (flat >> 3);
    const int m0 = (wg >> gxsh) * 128;
    const int n0 = (wg & ((1 << gxsh) - 1)) * 128;

    const int srow = lane >> 2;
    const int schunk = (((lane & 3) - ((lane >> 3) & 3)) & 3) * 8;
    const int ii0 = wv * 2, ii1 = wv * 2 + 1;
    const unsigned short* asrc0 = Ub + (size_t)(m0 + ii0 * 16 + srow) * WpA + schunk;
    const unsigned short* asrc1 = Ub + (size_t)(m0 + ii1 * 16 + srow) * WpA + schunk;
    const unsigned short* bsrc0 = xT + (size_t)(n0 + ii0 * 16 + srow) * WpB + schunk;
    const unsigned short* bsrc1 = xT + (size_t)(n0 + ii1 * 16 + srow) * WpB + schunk;

    const int fslot = (((lane >> 4) + (lr >> 1)) & 3) * 8;
    const int wrow = (wv >> 1) * 64;
    const int wcol = (wv & 1) * 64;
    const int u0 = wv * 1024;

    f32x4 acc[4][4];
#pragma unroll
    for (int i = 0; i < 4; ++i)
#pragma unroll
        for (int j = 0; j < 4; ++j) acc[i][j] = {0.f, 0.f, 0.f, 0.f};

#define UPS_STAGE(off_, B_)                                             \
    {                                                                   \
        gload16(asrc0 + (off_), &As[B_][u0]);                           \
        gload16(bsrc0 + (off_), &Bs[B_][u0]);                           \
        gload16(asrc1 + (off_), &As[B_][u0 + 512]);                     \
        gload16(bsrc1 + (off_), &Bs[B_][u0 + 512]);                     \
    }
#define UPS_COMPUTE(B_)                                                 \
    {                                                                   \
        bf16x8 af[4], bg[4];                                            \
        _Pragma("unroll")                                               \
        for (int mt = 0; mt < 4; ++mt)                                  \
            af[mt] = *(const bf16x8*)&As[B_][(wrow + mt * 16 + lr) * 32 + fslot]; \
        _Pragma("unroll")                                               \
        for (int nt = 0; nt < 4; ++nt)                                  \
            bg[nt] = *(const bf16x8*)&Bs[B_][(wcol + nt * 16 + lr) * 32 + fslot]; \
        _Pragma("unroll")                                               \
        for (int mt = 0; mt < 4; ++mt)                                  \
            _Pragma("unroll")                                           \
            for (int nt = 0; nt < 4; ++nt)                              \
                acc[mt][nt] = __builtin_amdgcn_mfma_f32_16x16x32_bf16(  \
                    af[mt], bg[nt], acc[mt][nt], 0, 0, 0);              \
    }
#define UPS_WAIT4 asm volatile("s_waitcnt vmcnt(4)" ::: "memory"); __builtin_amdgcn_s_barrier();
#define UPS_WAIT0 asm volatile("s_waitcnt vmcnt(0)" ::: "memory"); __builtin_amdgcn_s_barrier();

    UPS_STAGE(0, 0);
    UPS_STAGE(32, 1);
    UPS_WAIT4;

    const int m = nsteps / 3;
    for (int it = 0; it < m - 1; ++it) {
        UPS_STAGE(64, 2);  UPS_COMPUTE(0); UPS_WAIT4;
        UPS_STAGE(96, 0);  UPS_COMPUTE(1); UPS_WAIT4;
        UPS_STAGE(128, 1); UPS_COMPUTE(2); UPS_WAIT4;
        asrc0 += 96; asrc1 += 96; bsrc0 += 96; bsrc1 += 96;
    }
    UPS_STAGE(64, 2);
    UPS_COMPUTE(0); UPS_WAIT4;
    UPS_COMPUTE(1); UPS_WAIT0;
    UPS_COMPUTE(2);
#undef UPS_STAGE
#undef UPS_COMPUTE
#undef UPS_WAIT4
#undef UPS_WAIT0

#pragma unroll
    for (int mt = 0; mt < 4; ++mt) {
        const int vb = m0 + wrow + mt * 16 + (lane >> 4) * 4;
#pragma unroll
        for (int nt = 0; nt < 4; ++nt) {
            const int col = n0 + wcol + nt * 16 + lr;
            const int b = col >> FSH, f = col & (F - 1);
            unsigned short* op = out + (size_t)b * VP * F + f;
#pragma unroll
            for (int j = 0; j < 4; ++j)
                op[(size_t)(vb + j) * F] = f2bf(acc[mt][nt][j]);
        }
    }
}

// ------- SpiralConv: barrierless 1-wave 32-row tiles, full unroll, Fin=128 -------
template<int VP, int NSTEPS, int KSP>
__global__ __launch_bounds__(64) void conv_mfma(
    const unsigned short* __restrict__ xu, const int* __restrict__ ST,
    const unsigned short* __restrict__ WT, const float* __restrict__ bias,
    unsigned short* __restrict__ outT,
    int VT, int Kdim, int Fout) {
    __shared__ __align__(16) unsigned short As[2][32 * 32];
    __shared__ __align__(16) unsigned short Bs[3][64 * 32];
    const int lane = threadIdx.x;
    const int lr = lane & 15;
    const int m0 = blockIdx.x * 32;
    const int n0 = blockIdx.y * 64;
    const int b = m0 / VP;
    const int v0 = m0 - b * VP;
    const unsigned short* xb = xu + (((size_t)b * VP) << 7);

    const int arow = lane >> 1;
    const int h = lane & 1;
    const int vg = (v0 + arow < VT) ? (v0 + arow) : (VT - 1);
    const int schunk = (((lane & 3) - ((lane >> 3) & 3)) & 3) * 8;
    const int fslot = (((lane >> 4) + (lr >> 1)) & 3) * 8;
    const int sw0 = arow * 32 + (((2 * h + 0 + ((lane >> 2) & 3)) & 3) * 8);
    const int sw1 = arow * 32 + (((2 * h + 1 + ((lane >> 2) & 3)) & 3) * 8);

    int idx[KSP];
#pragma unroll
    for (int k = 0; k < KSP; ++k) idx[k] = ST[(size_t)k * VT + vg];

    f32x4 acc[2][4];
#pragma unroll
    for (int i = 0; i < 2; ++i)
#pragma unroll
        for (int j = 0; j < 4; ++j) acc[i][j] = {0.f, 0.f, 0.f, 0.f};

    bf16x8 gA[2][2];

#define CC(AB_, BB_)                                                    \
    {                                                                   \
        bf16x8 af[2], bg[4];                                            \
        _Pragma("unroll")                                               \
        for (int mt = 0; mt < 2; ++mt)                                  \
            af[mt] = *(const bf16x8*)&As[AB_][(mt * 16 + lr) * 32 + fslot]; \
        _Pragma("unroll")                                               \
        for (int nt = 0; nt < 4; ++nt)                                  \
            bg[nt] = *(const bf16x8*)&Bs[BB_][(nt * 16 + lr) * 32 + fslot]; \
        _Pragma("unroll")                                               \
        for (int mt = 0; mt < 2; ++mt)                                  \
            _Pragma("unroll")                                           \
            for (int nt = 0; nt < 4; ++nt)                              \
                acc[mt][nt] = __builtin_amdgcn_mfma_f32_16x16x32_bf16(  \
                    af[mt], bg[nt], acc[mt][nt], 0, 0, 0);              \
    }

    {
        const unsigned short* p = xb + (((size_t)idx[0]) << 7) + h * 16;
        gA[0][0] = *(const bf16x8*)(p);
        gA[0][1] = *(const bf16x8*)(p + 8);
#pragma unroll
        for (int i = 0; i < 4; ++i) {
            const int n = n0 + i * 16 + (lane >> 2);
            gload16(WT + (size_t)n * Kdim + schunk, &Bs[0][i * 512]);
        }
#pragma unroll
        for (int i = 0; i < 4; ++i) {
            const int n = n0 + i * 16 + (lane >> 2);
            gload16(WT + (size_t)n * Kdim + 32 + schunk, &Bs[1][i * 512]);
        }
        *(bf16x8*)&As[0][sw0] = gA[0][0];
        *(bf16x8*)&As[0][sw1] = gA[0][1];
        asm volatile("s_waitcnt vmcnt(4)" ::: "memory");
    }

#pragma unroll
    for (int ts = 0; ts < NSTEPS - 2; ++ts) {
        const int tn1 = ts + 1, tn2 = ts + 2;
        {
            const unsigned short* p =
                xb + (((size_t)idx[tn1 >> 2]) << 7) + (tn1 & 3) * 32 + h * 16;
            gA[tn1 & 1][0] = *(const bf16x8*)(p);
            gA[tn1 & 1][1] = *(const bf16x8*)(p + 8);
        }
        {
            const int k0 = tn2 * 32;
#pragma unroll
            for (int i = 0; i < 4; ++i) {
                const int n = n0 + i * 16 + (lane >> 2);
                gload16(WT + (size_t)n * Kdim + k0 + schunk, &Bs[tn2 % 3][i * 512]);
            }
        }
        CC(ts & 1, ts % 3);
        asm volatile("s_waitcnt vmcnt(4)" ::: "memory");
        *(bf16x8*)&As[tn1 & 1][sw0] = gA[tn1 & 1][0];
        *(bf16x8*)&As[tn1 & 1][sw1] = gA[tn1 & 1][1];
    }
    {
        const int tn1 = NSTEPS - 1;
        const unsigned short* p =
            xb + (((size_t)idx[tn1 >> 2]) << 7) + (tn1 & 3) * 32 + h * 16;
        gA[tn1 & 1][0] = *(const bf16x8*)(p);
        gA[tn1 & 1][1] = *(const bf16x8*)(p + 8);
        CC((NSTEPS - 2) & 1, (NSTEPS - 2) % 3);
        asm volatile("s_waitcnt vmcnt(0)" ::: "memory");
        *(bf16x8*)&As[tn1 & 1][sw0] = gA[tn1 & 1][0];
        *(bf16x8*)&As[tn1 & 1][sw1] = gA[tn1 & 1][1];
    }
    CC((NSTEPS - 1) & 1, (NSTEPS - 1) % 3);
#undef CC

#pragma unroll
    for (int nt = 0; nt < 4; ++nt) {
        const int n = n0 + nt * 16 + lr;
        const float bv = bias[n];
        unsigned short* op = outT + (size_t)(b * Fout + n) * VP;
#pragma unroll
        for (int mt = 0; mt < 2; ++mt) {
            const int v = v0 + mt * 16 + (lane >> 4) * 4;
            ushort4 stv;
#pragma unroll
            for (int j = 0; j < 4; ++j) {
                float val = acc[mt][nt][j] + bv;
                val = val > 0.f ? val : expm1f(val);
                if (v + j == VT - 1) val = 0.f;
                ((unsigned short*)&stv)[j] = f2bf(val);
            }
            *(ushort4*)(op + v) = stv;
        }
    }
}

// ------- Final conv: barrierless 1-wave 32-row tiles, full unroll, Fin=64, K=1280 -------
__global__ __launch_bounds__(64) void out_mfma(
    const unsigned short* __restrict__ xu, const int* __restrict__ ST,
    const unsigned short* __restrict__ W2T, const float* __restrict__ b2,
    float* __restrict__ out) {
    const int VT = 11794, VP = 11904, TPB = 372, NSTEPS = 40;
    __shared__ __align__(16) unsigned short As[2][32 * 32];
    const int lane = threadIdx.x;
    const int lr = lane & 15;
    const int lko = (lane >> 4) * 8;
    const int bm = blockIdx.x;
    const int b = bm / TPB;
    const int v0 = (bm - b * TPB) * 32;
    const unsigned short* xb = xu + ((size_t)b * VP << 6);

    const int arow = lane >> 1;
    const int h = lane & 1;
    const int v = v0 + arow;
    const int vg = v < VT ? v : VT - 1;
    const int sw0 = arow * 32 + (((2 * h + 0 + ((lane >> 2) & 3)) & 3) * 8);
    const int sw1 = arow * 32 + (((2 * h + 1 + ((lane >> 2) & 3)) & 3) * 8);
    const int fslot = (((lane >> 4) + (lr >> 1)) & 3) * 8;

    int idx[20];
#pragma unroll
    for (int k = 0; k < 20; ++k) idx[k] = ST[(size_t)k * VT + vg];

    f32x4 acc[2];
    acc[0] = {0.f, 0.f, 0.f, 0.f};
    acc[1] = {0.f, 0.f, 0.f, 0.f};

    const unsigned short* wrow = W2T + (size_t)lr * 1288 + lko;
    bf16x8 gA[2][2], bgr[2];

#define OC(AB_, WB_)                                                    \
    {                                                                   \
        bf16x8 af[2];                                                   \
        _Pragma("unroll")                                               \
        for (int mt = 0; mt < 2; ++mt)                                  \
            af[mt] = *(const bf16x8*)&As[AB_][(mt * 16 + lr) * 32 + fslot]; \
        _Pragma("unroll")                                               \
        for (int mt = 0; mt < 2; ++mt)                                  \
            acc[mt] = __builtin_amdgcn_mfma_f32_16x16x32_bf16(          \
                af[mt], bgr[WB_], acc[mt], 0, 0, 0);                    \
    }

    {
        const unsigned short* p = xb + (((size_t)idx[0]) << 6) + h * 16;
        gA[0][0] = *(const bf16x8*)(p);
        gA[0][1] = *(const bf16x8*)(p + 8);
        bgr[0] = *(const bf16x8*)(wrow);
        *(bf16x8*)&As[0][sw0] = gA[0][0];
        *(bf16x8*)&As[0][sw1] = gA[0][1];
    }

#pragma unroll
    for (int ts = 0; ts < NSTEPS - 1; ++ts) {
        const int tn = ts + 1;
        const unsigned short* p =
            xb + (((size_t)idx[tn >> 1]) << 6) + (tn & 1) * 32 + h * 16;
        gA[tn & 1][0] = *(const bf16x8*)(p);
        gA[tn & 1][1] = *(const bf16x8*)(p + 8);
        bgr[tn & 1] = *(const bf16x8*)(wrow + tn * 32);
        OC(ts & 1, ts & 1);
        *(bf16x8*)&As[tn & 1][sw0] = gA[tn & 1][0];
        *(bf16x8*)&As[tn & 1][sw1] = gA[tn & 1][1];
    }
    OC((NSTEPS - 1) & 1, (NSTEPS - 1) & 1);
#undef OC

    if (lr < 3) {
        const float bv = b2[lr];
#pragma unroll
        for (int mt = 0; mt < 2; ++mt) {
#pragma unroll
            for (int j = 0; j < 4; ++j) {
                const int vv = v0 + mt * 16 + (lane >> 4) * 4 + j;
                if (vv < VT) {
                    float val = acc[mt][j] + bv;
                    if (vv == VT - 1) val = 0.f;
                    out[((size_t)b * VT + vv) * 3 + lr] = val;
                }
            }
        }
    }
}

extern "C" void kernel_launch(void* const* d_in, const int* in_sizes, int n_in,
                              void* d_out, int out_size, void* d_ws, size_t ws_size,
                              hipStream_t stream) {
    const float* z   = (const float*)d_in[0];
    const float* U0  = (const float*)d_in[1];
    const float* U1  = (const float*)d_in[2];
    const float* U2  = (const float*)d_in[3];
    const int*   S0  = (const int*)d_in[4];
    const int*   S1  = (const int*)d_in[5];
    const int*   S2  = (const int*)d_in[6];
    const float* Wfc = (const float*)d_in[7];
    const float* bfc = (const float*)d_in[8];
    const float* W0  = (const float*)d_in[9];
    const float* b0  = (const float*)d_in[10];
    const float* W1  = (const float*)d_in[11];
    const float* b1  = (const float*)d_in[12];
    const float* W2  = (const float*)d_in[13];
    const float* b2  = (const float*)d_in[14];
    float* out = (float*)d_out;

    char* ws = (char*)d_ws;
    unsigned short* Ub0 = (unsigned short*)(ws + 0);          // [11904][2976]
    unsigned short* Ub1 = (unsigned short*)(ws + 70852608);   // [3072][768]
    unsigned short* Ub2 = (unsigned short*)(ws + 75571200);   // [768][192]
    unsigned short* x3T = (unsigned short*)(ws + 75866112);   // [2048][192]
    unsigned short* x2u = (unsigned short*)(ws + 76652544);   // [16][768][128]
    unsigned short* x2T = (unsigned short*)(ws + 79798272);   // [2048][768]
    unsigned short* x1u = (unsigned short*)(ws + 82944000);   // [16][3072][128]
    unsigned short* x1T = (unsigned short*)(ws + 95526912);   // [1024][3072]
    unsigned short* x0u = (unsigned short*)(ws + 101818368);  // [16][11904][64]
    unsigned short* W0T = (unsigned short*)(ws + 126197760);  // [128][1536]
    unsigned short* W1T = (unsigned short*)(ws + 126590976);  // [64][1792]
    int* S1T = (int*)(ws + 126820352);                        // [14][2949]
    int* S2T = (int*)(ws + 126985504);                        // [12][738]
    int* S0T = (int*)(ws + 127020928);                        // [20][11794]
    unsigned short* W2T = (unsigned short*)(ws + 127964448);  // [16][1288]

    cvt_u_all<<<dim3(2048), 256, 0, stream>>>(U0, U1, U2,
        (unsigned int*)Ub0, (unsigned int*)Ub1, (unsigned int*)Ub2);
    {
        const int total = 128 * 1536 + 64 * 1792 + 16 * 1288 +
                          20 * 11794 + 14 * 2949 + 12 * 738;
        cvt_misc<<<dim3((total + 255) / 256), 256, 0, stream>>>(
            W0, W1, W2, S0, S1, S2, W0T, W1T, W2T, S0T, S1T, S2T);
    }

    // 1. FC -> x3T (incl. pad-zero)
    fc_kernel<<<dim3((185 * 128 + 255) / 256), 256, 0, stream>>>(z, Wfc, bfc, x3T);
    // 2. U2 upsample -> x2u : nsteps=6
    ups_mfma<7, 768><<<dim3(96), 256, 0, stream>>>(Ub2, x3T, x2u, 192, 192, 6, 4, 12);
    // 3. conv0 (K=12,128->128,elu) -> x2T : barrierless, NSTEPS=48
    conv_mfma<768, 48, 12><<<dim3(384, 2), 64, 0, stream>>>(
        x2u, S2T, W0T, b0, x2T, 738, 1536, 128);
    // 4. U1 upsample -> x1u : nsteps=24
    ups_mfma<7, 3072><<<dim3(384), 256, 0, stream>>>(Ub1, x2T, x1u, 768, 768, 24, 4, 48);
    // 5. conv1 (K=14,128->64,elu) -> x1T : barrierless, NSTEPS=56
    conv_mfma<3072, 56, 14><<<dim3(1536, 1), 64, 0, stream>>>(
        x1u, S1T, W1T, b1, x1T, 2949, 1792, 64);
    // 6. U0 upsample -> x0u : nsteps=93
    ups_mfma<6, 11904><<<dim3(744), 256, 0, stream>>>(Ub0, x1T, x0u, 2976, 3072, 93, 3, 93);
    // 7. conv2 (K=20, 64->3) -> d_out : barrierless, NSTEPS=40
    out_mfma<<<dim3(16 * 372), 64, 0, stream>>>(x0u, S0T, W2T, b2, out);
}